// Round 1
// baseline (8666.374 us; speedup 1.0000x reference)
//
#include <hip/hip_runtime.h>
#include <math.h>

#define TPB 256

// ---------------- small elementwise / degree kernels ----------------

__global__ void k_fill1(float* p, int n) {
    int i = blockIdx.x * TPB + threadIdx.x;
    if (i < n) p[i] = 1.0f;   // self-loop contributes 1 to every degree
}

__global__ void k_fill0(float* p, int n) {
    int i = blockIdx.x * TPB + threadIdx.x;
    if (i < n) p[i] = 0.0f;
}

__global__ void k_count(const int* __restrict__ dst, float* __restrict__ deg, int E) {
    int e = blockIdx.x * TPB + threadIdx.x;
    if (e < E) atomicAdd(&deg[dst[e]], 1.0f);
}

__global__ void k_invsqrt(float* p, int n) {
    int i = blockIdx.x * TPB + threadIdx.x;
    if (i < n) p[i] = 1.0f / sqrtf(p[i]);   // deg >= 1 always (self loops)
}

__global__ void k_norm(const int* __restrict__ src, const int* __restrict__ dst,
                       const float* __restrict__ dis, float* __restrict__ nrm, int E) {
    int e = blockIdx.x * TPB + threadIdx.x;
    if (e < E) nrm[e] = dis[src[e]] * dis[dst[e]];
}

// ---------------- fp32 tiled GEMM: C[M,N] = A[M,K] @ B[K,N] ----------------
// 128x128 tile, BK=16, 256 threads, 8x8 per-thread microtile.

__global__ __launch_bounds__(256)
void k_gemm_f32(const float* __restrict__ A, const float* __restrict__ B,
                float* __restrict__ C, int M, int N, int K) {
    __shared__ float As[16][128];
    __shared__ float Bs[16][128];
    const int t  = threadIdx.x;
    const int m0 = blockIdx.y * 128, n0 = blockIdx.x * 128;
    const int tm = (t >> 4) * 8, tn = (t & 15) * 8;
    const int lr0 = t >> 2, lkg = (t & 3) * 4;   // A tile: row, k-group
    const int bk0 = t >> 5, bc = (t & 31) * 4;   // B tile: k-row, col

    int ar0 = m0 + lr0;      if (ar0 >= M) ar0 = M - 1;
    int ar1 = m0 + lr0 + 64; if (ar1 >= M) ar1 = M - 1;

    float acc[8][8] = {};
    for (int k0 = 0; k0 < K; k0 += 16) {
        float4 a0 = *(const float4*)(A + (size_t)ar0 * K + k0 + lkg);
        float4 a1 = *(const float4*)(A + (size_t)ar1 * K + k0 + lkg);
        float4 b0 = *(const float4*)(B + (size_t)(k0 + bk0) * N + n0 + bc);
        float4 b1 = *(const float4*)(B + (size_t)(k0 + bk0 + 8) * N + n0 + bc);
        __syncthreads();
        As[lkg + 0][lr0] = a0.x; As[lkg + 1][lr0] = a0.y;
        As[lkg + 2][lr0] = a0.z; As[lkg + 3][lr0] = a0.w;
        As[lkg + 0][lr0 + 64] = a1.x; As[lkg + 1][lr0 + 64] = a1.y;
        As[lkg + 2][lr0 + 64] = a1.z; As[lkg + 3][lr0 + 64] = a1.w;
        *(float4*)&Bs[bk0][bc]     = b0;
        *(float4*)&Bs[bk0 + 8][bc] = b1;
        __syncthreads();
#pragma unroll
        for (int k = 0; k < 16; ++k) {
            float a[8], b[8];
            *(float4*)(a)     = *(const float4*)&As[k][tm];
            *(float4*)(a + 4) = *(const float4*)&As[k][tm + 4];
            *(float4*)(b)     = *(const float4*)&Bs[k][tn];
            *(float4*)(b + 4) = *(const float4*)&Bs[k][tn + 4];
#pragma unroll
            for (int i = 0; i < 8; ++i)
#pragma unroll
                for (int j = 0; j < 8; ++j)
                    acc[i][j] = fmaf(a[i], b[j], acc[i][j]);
        }
    }
#pragma unroll
    for (int i = 0; i < 8; ++i) {
        int row = m0 + tm + i;
        if (row < M) {
            *(float4*)(C + (size_t)row * N + n0 + tn)     = *(float4*)&acc[i][0];
            *(float4*)(C + (size_t)row * N + n0 + tn + 4) = *(float4*)&acc[i][4];
        }
    }
}

// ---------------- aggregation ----------------
// out[v] = xw[v]*dis[v]^2 + bias   (self loop + bias)
__global__ void k_agg_init(const float* __restrict__ xw, const float* __restrict__ dis,
                           const float* __restrict__ bias, float* __restrict__ out, int n) {
    int idx = blockIdx.x * TPB + threadIdx.x;   // n*128 float4 chunks
    if (idx >= n * 128) return;
    int v = idx >> 7, cg = (idx & 127) * 4;
    float d = dis[v]; float d2 = d * d;
    float4 x = *(const float4*)(xw + (size_t)v * 512 + cg);
    float4 o;
    o.x = fmaf(x.x, d2, bias[cg + 0]);
    o.y = fmaf(x.y, d2, bias[cg + 1]);
    o.z = fmaf(x.z, d2, bias[cg + 2]);
    o.w = fmaf(x.w, d2, bias[cg + 3]);
    *(float4*)(out + (size_t)v * 512 + cg) = o;
}

// out[dst[e]] += xw[src[e]] * norm[e]
__global__ void k_agg_scatter(const float* __restrict__ xw, const int* __restrict__ src,
                              const int* __restrict__ dst, const float* __restrict__ nrm,
                              float* __restrict__ out, int total) {
    int idx = blockIdx.x * TPB + threadIdx.x;   // E*128 float4 chunks
    if (idx >= total) return;
    int e = idx >> 7, cg = (idx & 127) * 4;
    int s = src[e], d = dst[e];
    float r = nrm[e];
    float4 v = *(const float4*)(xw + (size_t)s * 512 + cg);
    float* o = out + (size_t)d * 512 + cg;
    atomicAdd(o + 0, v.x * r);
    atomicAdd(o + 1, v.y * r);
    atomicAdd(o + 2, v.z * r);
    atomicAdd(o + 3, v.w * r);
}

__global__ void k_relu(float* p, int n4) {
    int idx = blockIdx.x * TPB + threadIdx.x;
    if (idx >= n4) return;
    float4 v = *(float4*)(p + (size_t)idx * 4);
    v.x = fmaxf(v.x, 0.f); v.y = fmaxf(v.y, 0.f);
    v.z = fmaxf(v.z, 0.f); v.w = fmaxf(v.w, 0.f);
    *(float4*)(p + (size_t)idx * 4) = v;
}

// ---------------- fused link predictor ----------------
// For pair tile [128] x col tile [128]: h = relu(concat(z[p0],z[p1]) @ W + b1),
// partial_logit = sum_j h[:,j]*w2[j]; atomicAdd into logits.
__global__ __launch_bounds__(256)
void k_lp(const float* __restrict__ z, const int* __restrict__ pair, int P,
          const float* __restrict__ W, const float* __restrict__ b1,
          const float* __restrict__ w2, float* __restrict__ logits) {
    __shared__ float As[16][128];
    __shared__ float Bs[16][128];
    __shared__ int   nd[2][128];
    __shared__ float part[128];
    const int t  = threadIdx.x;
    const int p0 = blockIdx.y * 128, n0 = blockIdx.x * 128;
    if (t < 128) {
        int pi = p0 + t; if (pi >= P) pi = P - 1;
        nd[0][t] = pair[pi];
        nd[1][t] = pair[P + pi];
        part[t] = 0.0f;
    }
    __syncthreads();
    const int tm = (t >> 4) * 8, tn = (t & 15) * 8;
    const int lr0 = t >> 2, lkg = (t & 3) * 4;
    const int bk0 = t >> 5, bc = (t & 31) * 4;
    float acc[8][8] = {};
    for (int k0 = 0; k0 < 1024; k0 += 16) {
        const int half = k0 >> 9, kk = k0 & 511;
        float4 a0 = *(const float4*)(z + (size_t)nd[half][lr0] * 512 + kk + lkg);
        float4 a1 = *(const float4*)(z + (size_t)nd[half][lr0 + 64] * 512 + kk + lkg);
        float4 b0 = *(const float4*)(W + (size_t)(k0 + bk0) * 512 + n0 + bc);
        float4 b1 = *(const float4*)(W + (size_t)(k0 + bk0 + 8) * 512 + n0 + bc);
        __syncthreads();
        As[lkg + 0][lr0] = a0.x; As[lkg + 1][lr0] = a0.y;
        As[lkg + 2][lr0] = a0.z; As[lkg + 3][lr0] = a0.w;
        As[lkg + 0][lr0 + 64] = a1.x; As[lkg + 1][lr0 + 64] = a1.y;
        As[lkg + 2][lr0 + 64] = a1.z; As[lkg + 3][lr0 + 64] = a1.w;
        *(float4*)&Bs[bk0][bc]     = b0;
        *(float4*)&Bs[bk0 + 8][bc] = b1;
        __syncthreads();
#pragma unroll
        for (int k = 0; k < 16; ++k) {
            float a[8], b[8];
            *(float4*)(a)     = *(const float4*)&As[k][tm];
            *(float4*)(a + 4) = *(const float4*)&As[k][tm + 4];
            *(float4*)(b)     = *(const float4*)&Bs[k][tn];
            *(float4*)(b + 4) = *(const float4*)&Bs[k][tn + 4];
#pragma unroll
            for (int i = 0; i < 8; ++i)
#pragma unroll
                for (int j = 0; j < 8; ++j)
                    acc[i][j] = fmaf(a[i], b[j], acc[i][j]);
        }
    }
    // epilogue: + b1, relu, dot with w2, reduce per pair-row
#pragma unroll
    for (int i = 0; i < 8; ++i) {
        float s = 0.f;
#pragma unroll
        for (int j = 0; j < 8; ++j) {
            int col = n0 + tn + j;
            float h = acc[i][j] + b1[col];
            h = fmaxf(h, 0.f);
            s = fmaf(h, w2[col], s);
        }
        atomicAdd(&part[tm + i], s);
    }
    __syncthreads();
    if (t < 128) {
        int pi = p0 + t;
        if (pi < P) atomicAdd(&logits[pi], part[t]);
    }
}

__global__ void k_sigmoid(const float* __restrict__ logits, const float* __restrict__ lpb2,
                          float* __restrict__ out, int P) {
    int i = blockIdx.x * TPB + threadIdx.x;
    if (i < P) out[i] = 1.0f / (1.0f + expf(-(logits[i] + lpb2[0])));
}

// ---------------- launcher ----------------

extern "C" void kernel_launch(void* const* d_in, const int* in_sizes, int n_in,
                              void* d_out, int out_size, void* d_ws, size_t ws_size,
                              hipStream_t stream) {
    const float* x    = (const float*)d_in[0];
    const int*   ei   = (const int*)d_in[1];
    const int*   ep   = (const int*)d_in[2];
    const float* W1   = (const float*)d_in[3];
    const float* b1   = (const float*)d_in[4];
    const float* W2   = (const float*)d_in[5];
    const float* b2   = (const float*)d_in[6];
    const float* lpW1 = (const float*)d_in[7];
    const float* lpb1 = (const float*)d_in[8];
    const float* lpW2 = (const float*)d_in[9];
    const float* lpb2 = (const float*)d_in[10];

    const int n = in_sizes[0] / 512;
    const int E = in_sizes[1] / 2;
    const int P = in_sizes[2] / 2;
    const int* src = ei;
    const int* dst = ei + E;

    char* w = (char*)d_ws;
    size_t off = 0;
    auto alloc = [&](size_t bytes) {
        void* p = w + off;
        off = (off + bytes + 255) & ~(size_t)255;
        return p;
    };
    float* dis    = (float*)alloc((size_t)n * 4);
    float* nrm    = (float*)alloc((size_t)E * 4);
    float* logits = (float*)alloc((size_t)P * 4);
    float* buf0   = (float*)alloc((size_t)n * 512 * 4);
    float* buf1   = (float*)alloc((size_t)n * 512 * 4);

    dim3 blk(TPB);
    // degrees + norm
    k_fill1<<<(n + TPB - 1) / TPB, blk, 0, stream>>>(dis, n);
    k_count<<<(E + TPB - 1) / TPB, blk, 0, stream>>>(dst, dis, E);
    k_invsqrt<<<(n + TPB - 1) / TPB, blk, 0, stream>>>(dis, n);
    k_norm<<<(E + TPB - 1) / TPB, blk, 0, stream>>>(src, dst, dis, nrm, E);

    const int gy = (n + 127) / 128;
    const int scat_total = E * 128;
    const int scat_blocks = (scat_total + TPB - 1) / TPB;
    const int ew_blocks = (n * 128 + TPB - 1) / TPB;

    // layer 1: xw = x@W1 ; z1 = agg(xw) + b1 ; relu
    k_gemm_f32<<<dim3(4, gy), blk, 0, stream>>>(x, W1, buf0, n, 512, 512);
    k_agg_init<<<ew_blocks, blk, 0, stream>>>(buf0, dis, b1, buf1, n);
    k_agg_scatter<<<scat_blocks, blk, 0, stream>>>(buf0, src, dst, nrm, buf1, scat_total);
    k_relu<<<ew_blocks, blk, 0, stream>>>(buf1, n * 128);

    // layer 2: xw2 = z1@W2 ; z2 = agg(xw2) + b2
    k_gemm_f32<<<dim3(4, gy), blk, 0, stream>>>(buf1, W2, buf0, n, 512, 512);
    k_agg_init<<<ew_blocks, blk, 0, stream>>>(buf0, dis, b2, buf1, n);
    k_agg_scatter<<<scat_blocks, blk, 0, stream>>>(buf0, src, dst, nrm, buf1, scat_total);

    // link predictor
    k_fill0<<<(P + TPB - 1) / TPB, blk, 0, stream>>>(logits, P);
    k_lp<<<dim3(4, (P + 127) / 128), blk, 0, stream>>>(buf1, ep, P, lpW1, lpb1, lpW2, logits);
    k_sigmoid<<<(P + TPB - 1) / TPB, blk, 0, stream>>>(logits, lpb2, (float*)d_out, P);
}

// Round 2
// 3372.167 us; speedup vs baseline: 2.5700x; 2.5700x over previous
//
#include <hip/hip_runtime.h>
#include <math.h>

#define TPB 256

// ---------------- degree / CSR build ----------------

__global__ void k_zero_int(int* p, int n) {
    int i = blockIdx.x * TPB + threadIdx.x;
    if (i < n) p[i] = 0;
}

__global__ void k_hist(const int* __restrict__ dst, int* __restrict__ cnt, int E) {
    int e = blockIdx.x * TPB + threadIdx.x;
    if (e < E) atomicAdd(&cnt[dst[e]], 1);
}

// single-block exclusive scan over cnt[0..n) -> row_start[0..n], cursor copy
__global__ __launch_bounds__(1024)
void k_scan(const int* __restrict__ cnt, int* __restrict__ row_start,
            int* __restrict__ cursor, int n) {
    __shared__ int sums[1024];
    const int t = threadIdx.x;
    const int chunk = (n + 1023) / 1024;
    const int beg = t * chunk;
    const int end = min(beg + chunk, n);
    int s = 0;
    for (int i = beg; i < end; ++i) s += cnt[i];
    sums[t] = s;
    __syncthreads();
    for (int d = 1; d < 1024; d <<= 1) {
        int v = (t >= d) ? sums[t - d] : 0;
        __syncthreads();
        sums[t] += v;
        __syncthreads();
    }
    int excl = (t == 0) ? 0 : sums[t - 1];
    for (int i = beg; i < end; ++i) {
        row_start[i] = excl;
        cursor[i] = excl;
        excl += cnt[i];
    }
    if (t == 1023) row_start[n] = sums[1023];
}

__global__ void k_dis(const int* __restrict__ cnt, float* __restrict__ dis, int n) {
    int i = blockIdx.x * TPB + threadIdx.x;
    if (i < n) dis[i] = rsqrtf((float)cnt[i] + 1.0f);   // +1 self loop
}

__global__ void k_fill_csr(const int* __restrict__ src, const int* __restrict__ dst,
                           const float* __restrict__ dis, int* __restrict__ cursor,
                           int* __restrict__ csr_src, float* __restrict__ csr_nrm, int E) {
    int e = blockIdx.x * TPB + threadIdx.x;
    if (e >= E) return;
    int s = src[e], d = dst[e];
    int pos = atomicAdd(&cursor[d], 1);
    csr_src[pos] = s;
    csr_nrm[pos] = dis[s] * dis[d];
}

// ---------------- fp32 tiled GEMM: C[M,N] = A[M,K] @ B[K,N] ----------------

__global__ __launch_bounds__(256)
void k_gemm_f32(const float* __restrict__ A, const float* __restrict__ B,
                float* __restrict__ C, int M, int N, int K) {
    __shared__ float As[16][128];
    __shared__ float Bs[16][128];
    const int t  = threadIdx.x;
    const int m0 = blockIdx.y * 128, n0 = blockIdx.x * 128;
    const int tm = (t >> 4) * 8, tn = (t & 15) * 8;
    const int lr0 = t >> 2, lkg = (t & 3) * 4;
    const int bk0 = t >> 5, bc = (t & 31) * 4;

    int ar0 = m0 + lr0;      if (ar0 >= M) ar0 = M - 1;
    int ar1 = m0 + lr0 + 64; if (ar1 >= M) ar1 = M - 1;

    float acc[8][8] = {};
    for (int k0 = 0; k0 < K; k0 += 16) {
        float4 a0 = *(const float4*)(A + (size_t)ar0 * K + k0 + lkg);
        float4 a1 = *(const float4*)(A + (size_t)ar1 * K + k0 + lkg);
        float4 b0 = *(const float4*)(B + (size_t)(k0 + bk0) * N + n0 + bc);
        float4 b1 = *(const float4*)(B + (size_t)(k0 + bk0 + 8) * N + n0 + bc);
        __syncthreads();
        As[lkg + 0][lr0] = a0.x; As[lkg + 1][lr0] = a0.y;
        As[lkg + 2][lr0] = a0.z; As[lkg + 3][lr0] = a0.w;
        As[lkg + 0][lr0 + 64] = a1.x; As[lkg + 1][lr0 + 64] = a1.y;
        As[lkg + 2][lr0 + 64] = a1.z; As[lkg + 3][lr0 + 64] = a1.w;
        *(float4*)&Bs[bk0][bc]     = b0;
        *(float4*)&Bs[bk0 + 8][bc] = b1;
        __syncthreads();
#pragma unroll
        for (int k = 0; k < 16; ++k) {
            float a[8], b[8];
            *(float4*)(a)     = *(const float4*)&As[k][tm];
            *(float4*)(a + 4) = *(const float4*)&As[k][tm + 4];
            *(float4*)(b)     = *(const float4*)&Bs[k][tn];
            *(float4*)(b + 4) = *(const float4*)&Bs[k][tn + 4];
#pragma unroll
            for (int i = 0; i < 8; ++i)
#pragma unroll
                for (int j = 0; j < 8; ++j)
                    acc[i][j] = fmaf(a[i], b[j], acc[i][j]);
        }
    }
#pragma unroll
    for (int i = 0; i < 8; ++i) {
        int row = m0 + tm + i;
        if (row < M) {
            *(float4*)(C + (size_t)row * N + n0 + tn)     = *(float4*)&acc[i][0];
            *(float4*)(C + (size_t)row * N + n0 + tn + 4) = *(float4*)&acc[i][4];
        }
    }
}

// ---------------- CSR gather aggregation ----------------
// out[v] = sum_{e: dst=v} xw[src_e]*nrm_e + xw[v]*dis[v]^2 + bias  (+relu)
// one wave (64 lanes) per node; lane covers float4 at lane*4 and 256+lane*4.
__global__ __launch_bounds__(256)
void k_agg_gather(const float* __restrict__ xw, const int* __restrict__ row_start,
                  const int* __restrict__ csr_src, const float* __restrict__ csr_nrm,
                  const float* __restrict__ dis, const float* __restrict__ bias,
                  float* __restrict__ out, int n, int do_relu) {
    const int v = (blockIdx.x * TPB + threadIdx.x) >> 6;
    if (v >= n) return;
    const int lane = threadIdx.x & 63;
    const int c0 = lane * 4, c1 = 256 + lane * 4;

    float d = dis[v]; float d2 = d * d;
    const float* xv = xw + (size_t)v * 512;
    float4 acc0 = *(const float4*)(xv + c0);
    float4 acc1 = *(const float4*)(xv + c1);
    float4 b0 = *(const float4*)(bias + c0);
    float4 b1 = *(const float4*)(bias + c1);
    acc0.x = fmaf(acc0.x, d2, b0.x); acc0.y = fmaf(acc0.y, d2, b0.y);
    acc0.z = fmaf(acc0.z, d2, b0.z); acc0.w = fmaf(acc0.w, d2, b0.w);
    acc1.x = fmaf(acc1.x, d2, b1.x); acc1.y = fmaf(acc1.y, d2, b1.y);
    acc1.z = fmaf(acc1.z, d2, b1.z); acc1.w = fmaf(acc1.w, d2, b1.w);

    const int beg = row_start[v], end = row_start[v + 1];
    for (int j = beg; j < end; ++j) {
        int s = csr_src[j];
        float r = csr_nrm[j];
        const float* xs = xw + (size_t)s * 512;
        float4 u0 = *(const float4*)(xs + c0);
        float4 u1 = *(const float4*)(xs + c1);
        acc0.x = fmaf(u0.x, r, acc0.x); acc0.y = fmaf(u0.y, r, acc0.y);
        acc0.z = fmaf(u0.z, r, acc0.z); acc0.w = fmaf(u0.w, r, acc0.w);
        acc1.x = fmaf(u1.x, r, acc1.x); acc1.y = fmaf(u1.y, r, acc1.y);
        acc1.z = fmaf(u1.z, r, acc1.z); acc1.w = fmaf(u1.w, r, acc1.w);
    }
    if (do_relu) {
        acc0.x = fmaxf(acc0.x, 0.f); acc0.y = fmaxf(acc0.y, 0.f);
        acc0.z = fmaxf(acc0.z, 0.f); acc0.w = fmaxf(acc0.w, 0.f);
        acc1.x = fmaxf(acc1.x, 0.f); acc1.y = fmaxf(acc1.y, 0.f);
        acc1.z = fmaxf(acc1.z, 0.f); acc1.w = fmaxf(acc1.w, 0.f);
    }
    float* o = out + (size_t)v * 512;
    *(float4*)(o + c0) = acc0;
    *(float4*)(o + c1) = acc1;
}

// ---------------- fused link predictor ----------------

__global__ void k_fill0(float* p, int n) {
    int i = blockIdx.x * TPB + threadIdx.x;
    if (i < n) p[i] = 0.0f;
}

__global__ __launch_bounds__(256)
void k_lp(const float* __restrict__ z, const int* __restrict__ pair, int P,
          const float* __restrict__ W, const float* __restrict__ b1,
          const float* __restrict__ w2, float* __restrict__ logits) {
    __shared__ float As[16][128];
    __shared__ float Bs[16][128];
    __shared__ int   nd[2][128];
    __shared__ float part[128];
    const int t  = threadIdx.x;
    const int p0 = blockIdx.y * 128, n0 = blockIdx.x * 128;
    if (t < 128) {
        int pi = p0 + t; if (pi >= P) pi = P - 1;
        nd[0][t] = pair[pi];
        nd[1][t] = pair[P + pi];
        part[t] = 0.0f;
    }
    __syncthreads();
    const int tm = (t >> 4) * 8, tn = (t & 15) * 8;
    const int lr0 = t >> 2, lkg = (t & 3) * 4;
    const int bk0 = t >> 5, bc = (t & 31) * 4;
    float acc[8][8] = {};
    for (int k0 = 0; k0 < 1024; k0 += 16) {
        const int half = k0 >> 9, kk = k0 & 511;
        float4 a0 = *(const float4*)(z + (size_t)nd[half][lr0] * 512 + kk + lkg);
        float4 a1 = *(const float4*)(z + (size_t)nd[half][lr0 + 64] * 512 + kk + lkg);
        float4 b0 = *(const float4*)(W + (size_t)(k0 + bk0) * 512 + n0 + bc);
        float4 b1 = *(const float4*)(W + (size_t)(k0 + bk0 + 8) * 512 + n0 + bc);
        __syncthreads();
        As[lkg + 0][lr0] = a0.x; As[lkg + 1][lr0] = a0.y;
        As[lkg + 2][lr0] = a0.z; As[lkg + 3][lr0] = a0.w;
        As[lkg + 0][lr0 + 64] = a1.x; As[lkg + 1][lr0 + 64] = a1.y;
        As[lkg + 2][lr0 + 64] = a1.z; As[lkg + 3][lr0 + 64] = a1.w;
        *(float4*)&Bs[bk0][bc]     = b0;
        *(float4*)&Bs[bk0 + 8][bc] = b1;
        __syncthreads();
#pragma unroll
        for (int k = 0; k < 16; ++k) {
            float a[8], b[8];
            *(float4*)(a)     = *(const float4*)&As[k][tm];
            *(float4*)(a + 4) = *(const float4*)&As[k][tm + 4];
            *(float4*)(b)     = *(const float4*)&Bs[k][tn];
            *(float4*)(b + 4) = *(const float4*)&Bs[k][tn + 4];
#pragma unroll
            for (int i = 0; i < 8; ++i)
#pragma unroll
                for (int j = 0; j < 8; ++j)
                    acc[i][j] = fmaf(a[i], b[j], acc[i][j]);
        }
    }
#pragma unroll
    for (int i = 0; i < 8; ++i) {
        float s = 0.f;
#pragma unroll
        for (int j = 0; j < 8; ++j) {
            int col = n0 + tn + j;
            float h = acc[i][j] + b1[col];
            h = fmaxf(h, 0.f);
            s = fmaf(h, w2[col], s);
        }
        atomicAdd(&part[tm + i], s);
    }
    __syncthreads();
    if (t < 128) {
        int pi = p0 + t;
        if (pi < P) atomicAdd(&logits[pi], part[t]);
    }
}

__global__ void k_sigmoid(const float* __restrict__ logits, const float* __restrict__ lpb2,
                          float* __restrict__ out, int P) {
    int i = blockIdx.x * TPB + threadIdx.x;
    if (i < P) out[i] = 1.0f / (1.0f + expf(-(logits[i] + lpb2[0])));
}

// ---------------- launcher ----------------

extern "C" void kernel_launch(void* const* d_in, const int* in_sizes, int n_in,
                              void* d_out, int out_size, void* d_ws, size_t ws_size,
                              hipStream_t stream) {
    const float* x    = (const float*)d_in[0];
    const int*   ei   = (const int*)d_in[1];
    const int*   ep   = (const int*)d_in[2];
    const float* W1   = (const float*)d_in[3];
    const float* b1   = (const float*)d_in[4];
    const float* W2   = (const float*)d_in[5];
    const float* b2   = (const float*)d_in[6];
    const float* lpW1 = (const float*)d_in[7];
    const float* lpb1 = (const float*)d_in[8];
    const float* lpW2 = (const float*)d_in[9];
    const float* lpb2 = (const float*)d_in[10];

    const int n = in_sizes[0] / 512;
    const int E = in_sizes[1] / 2;
    const int P = in_sizes[2] / 2;
    const int* src = ei;
    const int* dst = ei + E;

    char* w = (char*)d_ws;
    size_t off = 0;
    auto alloc = [&](size_t bytes) {
        void* p = w + off;
        off = (off + bytes + 255) & ~(size_t)255;
        return p;
    };
    int*   cnt      = (int*)alloc((size_t)n * 4);
    int*   row_start= (int*)alloc((size_t)(n + 1) * 4);
    int*   cursor   = (int*)alloc((size_t)n * 4);
    int*   csr_src  = (int*)alloc((size_t)E * 4);
    float* csr_nrm  = (float*)alloc((size_t)E * 4);
    float* dis      = (float*)alloc((size_t)n * 4);
    float* logits   = (float*)alloc((size_t)P * 4);
    float* buf0     = (float*)alloc((size_t)n * 512 * 4);
    float* buf1     = (float*)alloc((size_t)n * 512 * 4);

    dim3 blk(TPB);
    const int nb_n = (n + TPB - 1) / TPB;
    const int nb_E = (E + TPB - 1) / TPB;

    // CSR build + norms
    k_zero_int<<<nb_n, blk, 0, stream>>>(cnt, n);
    k_hist<<<nb_E, blk, 0, stream>>>(dst, cnt, E);
    k_scan<<<1, 1024, 0, stream>>>(cnt, row_start, cursor, n);
    k_dis<<<nb_n, blk, 0, stream>>>(cnt, dis, n);
    k_fill_csr<<<nb_E, blk, 0, stream>>>(src, dst, dis, cursor, csr_src, csr_nrm, E);

    const int gy = (n + 127) / 128;
    const int agg_blocks = (n * 64 + TPB - 1) / TPB;   // one wave per node

    // layer 1
    k_gemm_f32<<<dim3(4, gy), blk, 0, stream>>>(x, W1, buf0, n, 512, 512);
    k_agg_gather<<<agg_blocks, blk, 0, stream>>>(buf0, row_start, csr_src, csr_nrm,
                                                 dis, b1, buf1, n, 1);
    // layer 2
    k_gemm_f32<<<dim3(4, gy), blk, 0, stream>>>(buf1, W2, buf0, n, 512, 512);
    k_agg_gather<<<agg_blocks, blk, 0, stream>>>(buf0, row_start, csr_src, csr_nrm,
                                                 dis, b2, buf1, n, 0);

    // link predictor
    k_fill0<<<(P + TPB - 1) / TPB, blk, 0, stream>>>(logits, P);
    k_lp<<<dim3(4, (P + 127) / 128), blk, 0, stream>>>(buf1, ep, P, lpW1, lpb1, lpW2, logits);
    k_sigmoid<<<(P + TPB - 1) / TPB, blk, 0, stream>>>(logits, lpb2, (float*)d_out, P);
}

// Round 3
// 872.557 us; speedup vs baseline: 9.9322x; 3.8647x over previous
//
#include <hip/hip_runtime.h>
#include <math.h>

#define TPB 256

typedef __attribute__((ext_vector_type(8))) short bf16x8;
typedef __attribute__((ext_vector_type(4))) float f32x4;

__device__ __forceinline__ unsigned cvt_bf(float f) {
    unsigned u = __float_as_uint(f);
    u += 0x7fffu + ((u >> 16) & 1u);   // round-to-nearest-even
    return u >> 16;
}
__device__ __forceinline__ unsigned pack2(float a, float b) {
    return cvt_bf(a) | (cvt_bf(b) << 16);
}

// ---------------- degree / CSR build ----------------

__global__ void k_zero_int(int* p, int n) {
    int i = blockIdx.x * TPB + threadIdx.x;
    if (i < n) p[i] = 0;
}

__global__ void k_hist(const int* __restrict__ dst, int* __restrict__ cnt, int E) {
    int e = blockIdx.x * TPB + threadIdx.x;
    if (e < E) atomicAdd(&cnt[dst[e]], 1);
}

__global__ __launch_bounds__(1024)
void k_scan(const int* __restrict__ cnt, int* __restrict__ row_start,
            int* __restrict__ cursor, int n) {
    __shared__ int sums[1024];
    const int t = threadIdx.x;
    const int chunk = (n + 1023) / 1024;
    const int beg = t * chunk;
    const int end = min(beg + chunk, n);
    int s = 0;
    for (int i = beg; i < end; ++i) s += cnt[i];
    sums[t] = s;
    __syncthreads();
    for (int d = 1; d < 1024; d <<= 1) {
        int v = (t >= d) ? sums[t - d] : 0;
        __syncthreads();
        sums[t] += v;
        __syncthreads();
    }
    int excl = (t == 0) ? 0 : sums[t - 1];
    for (int i = beg; i < end; ++i) {
        row_start[i] = excl;
        cursor[i] = excl;
        excl += cnt[i];
    }
    if (t == 1023) row_start[n] = sums[1023];
}

__global__ void k_dis(const int* __restrict__ cnt, float* __restrict__ dis, int n) {
    int i = blockIdx.x * TPB + threadIdx.x;
    if (i < n) dis[i] = rsqrtf((float)cnt[i] + 1.0f);
}

__global__ void k_fill_csr(const int* __restrict__ src, const int* __restrict__ dst,
                           const float* __restrict__ dis, int* __restrict__ cursor,
                           int* __restrict__ csr_src, float* __restrict__ csr_nrm, int E) {
    int e = blockIdx.x * TPB + threadIdx.x;
    if (e >= E) return;
    int s = src[e], d = dst[e];
    int pos = atomicAdd(&cursor[d], 1);
    csr_src[pos] = s;
    csr_nrm[pos] = dis[s] * dis[d];
}

// ---------------- conversions ----------------

__global__ void k_f2bf(const float* __restrict__ in, unsigned short* __restrict__ out, int total8) {
    int i = blockIdx.x * TPB + threadIdx.x;
    if (i >= total8) return;
    float4 f0 = *(const float4*)(in + (size_t)i * 8);
    float4 f1 = *(const float4*)(in + (size_t)i * 8 + 4);
    uint4 o;
    o.x = pack2(f0.x, f0.y); o.y = pack2(f0.z, f0.w);
    o.z = pack2(f1.x, f1.y); o.w = pack2(f1.z, f1.w);
    *(uint4*)(out + (size_t)i * 8) = o;
}

// out[n][k] = bf16(in[k][n])
__global__ void k_cvtT(const float* __restrict__ in, unsigned short* __restrict__ out, int K, int N) {
    int id = blockIdx.x * TPB + threadIdx.x;
    if (id >= K * N) return;
    int k = id / N, nn = id % N;
    out[(size_t)nn * K + k] = (unsigned short)cvt_bf(in[id]);
}

// ---------------- bf16 MFMA GEMM: C[M,N] = A[M,K] @ Bt[N,K]^T ----------------
// 128x128 tile, BK=32, 4 waves, wave = 64x64 (4x4 frags of 16x16x32).

__global__ __launch_bounds__(256)
void k_gemm_bf(const unsigned short* __restrict__ A, const unsigned short* __restrict__ Bt,
               float* __restrict__ C, int M, int N, int K) {
    __shared__ unsigned short Asl[128 * 40];   // row-major, pad to 40 (80B rows)
    __shared__ unsigned short Bsl[128 * 40];
    const int t = threadIdx.x;
    const int m0 = blockIdx.y * 128, n0 = blockIdx.x * 128;
    const int wid = t >> 6, l = t & 63;
    const int wr = (wid >> 1) * 64, wc = (wid & 1) * 64;
    const int lrow = l & 15, g = l >> 4;
    const int r = t >> 1, c = t & 1;
    const int arow = min(m0 + r, M - 1);
    const unsigned short* pa = A + (size_t)arow * K + c * 16;
    const unsigned short* pb = Bt + (size_t)(n0 + r) * K + c * 16;
    unsigned short* wA = &Asl[r * 40 + c * 16];
    unsigned short* wB = &Bsl[r * 40 + c * 16];

    f32x4 acc[4][4] = {};
    for (int k0 = 0; k0 < K; k0 += 32) {
        uint4 a0 = *(const uint4*)(pa + k0);
        uint4 a1 = *(const uint4*)(pa + k0 + 8);
        uint4 b0 = *(const uint4*)(pb + k0);
        uint4 b1 = *(const uint4*)(pb + k0 + 8);
        __syncthreads();
        *(uint4*)wA = a0; *(uint4*)(wA + 8) = a1;
        *(uint4*)wB = b0; *(uint4*)(wB + 8) = b1;
        __syncthreads();
        bf16x8 af[4], bfr[4];
#pragma unroll
        for (int i = 0; i < 4; ++i)
            af[i] = *(const bf16x8*)&Asl[(wr + i * 16 + lrow) * 40 + g * 8];
#pragma unroll
        for (int j = 0; j < 4; ++j)
            bfr[j] = *(const bf16x8*)&Bsl[(wc + j * 16 + lrow) * 40 + g * 8];
#pragma unroll
        for (int i = 0; i < 4; ++i)
#pragma unroll
            for (int j = 0; j < 4; ++j)
                acc[i][j] = __builtin_amdgcn_mfma_f32_16x16x32_bf16(af[i], bfr[j], acc[i][j], 0, 0, 0);
    }
#pragma unroll
    for (int i = 0; i < 4; ++i) {
        const int rb = m0 + wr + i * 16 + g * 4;
#pragma unroll
        for (int e = 0; e < 4; ++e) {
            const int row = rb + e;
            if (row < M) {
#pragma unroll
                for (int j = 0; j < 4; ++j)
                    C[(size_t)row * N + n0 + wc + j * 16 + lrow] = acc[i][j][e];
            }
        }
    }
}

// ---------------- CSR gather aggregation (fp32 in, bf16 out) ----------------

__global__ __launch_bounds__(256)
void k_agg_gather(const float* __restrict__ xw, const int* __restrict__ row_start,
                  const int* __restrict__ csr_src, const float* __restrict__ csr_nrm,
                  const float* __restrict__ dis, const float* __restrict__ bias,
                  unsigned short* __restrict__ out, int n, int do_relu) {
    const int v = (blockIdx.x * TPB + threadIdx.x) >> 6;
    if (v >= n) return;
    const int lane = threadIdx.x & 63;
    const int c0 = lane * 4, c1 = 256 + lane * 4;

    float d = dis[v]; float d2 = d * d;
    const float* xv = xw + (size_t)v * 512;
    float4 acc0 = *(const float4*)(xv + c0);
    float4 acc1 = *(const float4*)(xv + c1);
    float4 b0 = *(const float4*)(bias + c0);
    float4 b1 = *(const float4*)(bias + c1);
    acc0.x = fmaf(acc0.x, d2, b0.x); acc0.y = fmaf(acc0.y, d2, b0.y);
    acc0.z = fmaf(acc0.z, d2, b0.z); acc0.w = fmaf(acc0.w, d2, b0.w);
    acc1.x = fmaf(acc1.x, d2, b1.x); acc1.y = fmaf(acc1.y, d2, b1.y);
    acc1.z = fmaf(acc1.z, d2, b1.z); acc1.w = fmaf(acc1.w, d2, b1.w);

    const int beg = row_start[v], end = row_start[v + 1];
    for (int j = beg; j < end; ++j) {
        int s = csr_src[j];
        float rr = csr_nrm[j];
        const float* xs = xw + (size_t)s * 512;
        float4 u0 = *(const float4*)(xs + c0);
        float4 u1 = *(const float4*)(xs + c1);
        acc0.x = fmaf(u0.x, rr, acc0.x); acc0.y = fmaf(u0.y, rr, acc0.y);
        acc0.z = fmaf(u0.z, rr, acc0.z); acc0.w = fmaf(u0.w, rr, acc0.w);
        acc1.x = fmaf(u1.x, rr, acc1.x); acc1.y = fmaf(u1.y, rr, acc1.y);
        acc1.z = fmaf(u1.z, rr, acc1.z); acc1.w = fmaf(u1.w, rr, acc1.w);
    }
    if (do_relu) {
        acc0.x = fmaxf(acc0.x, 0.f); acc0.y = fmaxf(acc0.y, 0.f);
        acc0.z = fmaxf(acc0.z, 0.f); acc0.w = fmaxf(acc0.w, 0.f);
        acc1.x = fmaxf(acc1.x, 0.f); acc1.y = fmaxf(acc1.y, 0.f);
        acc1.z = fmaxf(acc1.z, 0.f); acc1.w = fmaxf(acc1.w, 0.f);
    }
    uint2 o0, o1;
    o0.x = pack2(acc0.x, acc0.y); o0.y = pack2(acc0.z, acc0.w);
    o1.x = pack2(acc1.x, acc1.y); o1.y = pack2(acc1.z, acc1.w);
    *(uint2*)(out + (size_t)v * 512 + c0) = o0;
    *(uint2*)(out + (size_t)v * 512 + c1) = o1;
}

// ---------------- fused link predictor (bf16 MFMA) ----------------

__global__ void k_fill0(float* p, int n) {
    int i = blockIdx.x * TPB + threadIdx.x;
    if (i < n) p[i] = 0.0f;
}

__global__ __launch_bounds__(256)
void k_lp_mfma(const unsigned short* __restrict__ z, const int* __restrict__ pair, int P,
               const unsigned short* __restrict__ Wt, const float* __restrict__ b1,
               const float* __restrict__ w2, float* __restrict__ logits) {
    __shared__ unsigned short Asl[128 * 40];
    __shared__ unsigned short Bsl[128 * 40];
    __shared__ int nd[2][128];
    const int t = threadIdx.x;
    const int p0 = blockIdx.y * 128, n0 = blockIdx.x * 128;
    if (t < 128) {
        int pi = min(p0 + t, P - 1);
        nd[0][t] = pair[pi];
        nd[1][t] = pair[P + pi];
    }
    __syncthreads();
    const int wid = t >> 6, l = t & 63;
    const int wr = (wid >> 1) * 64, wc = (wid & 1) * 64;
    const int lrow = l & 15, g = l >> 4;
    const int r = t >> 1, c = t & 1;
    const unsigned short* pb = Wt + (size_t)(n0 + r) * 1024 + c * 16;
    unsigned short* wA = &Asl[r * 40 + c * 16];
    unsigned short* wB = &Bsl[r * 40 + c * 16];

    f32x4 acc[4][4] = {};
    for (int k0 = 0; k0 < 1024; k0 += 32) {
        const int node = nd[k0 >> 9][r];
        const unsigned short* pa = z + (size_t)node * 512 + (k0 & 511) + c * 16;
        uint4 a0 = *(const uint4*)pa;
        uint4 a1 = *(const uint4*)(pa + 8);
        uint4 b0 = *(const uint4*)(pb + k0);
        uint4 b1 = *(const uint4*)(pb + k0 + 8);
        __syncthreads();
        *(uint4*)wA = a0; *(uint4*)(wA + 8) = a1;
        *(uint4*)wB = b0; *(uint4*)(wB + 8) = b1;
        __syncthreads();
        bf16x8 af[4], bfr[4];
#pragma unroll
        for (int i = 0; i < 4; ++i)
            af[i] = *(const bf16x8*)&Asl[(wr + i * 16 + lrow) * 40 + g * 8];
#pragma unroll
        for (int j = 0; j < 4; ++j)
            bfr[j] = *(const bf16x8*)&Bsl[(wc + j * 16 + lrow) * 40 + g * 8];
#pragma unroll
        for (int i = 0; i < 4; ++i)
#pragma unroll
            for (int j = 0; j < 4; ++j)
                acc[i][j] = __builtin_amdgcn_mfma_f32_16x16x32_bf16(af[i], bfr[j], acc[i][j], 0, 0, 0);
    }
    // epilogue: +b1, relu, dot w2, reduce over the 16 cols each lane-group holds
    float b1v[4], w2v[4];
#pragma unroll
    for (int j = 0; j < 4; ++j) {
        int col = n0 + wc + j * 16 + lrow;
        b1v[j] = b1[col];
        w2v[j] = w2[col];
    }
#pragma unroll
    for (int i = 0; i < 4; ++i)
#pragma unroll
        for (int e = 0; e < 4; ++e) {
            float s = 0.f;
#pragma unroll
            for (int j = 0; j < 4; ++j) {
                float h = acc[i][j][e] + b1v[j];
                h = fmaxf(h, 0.f);
                s = fmaf(h, w2v[j], s);
            }
            s += __shfl_xor(s, 1, 64);
            s += __shfl_xor(s, 2, 64);
            s += __shfl_xor(s, 4, 64);
            s += __shfl_xor(s, 8, 64);
            if (lrow == 0) {
                int pi = p0 + wr + i * 16 + g * 4 + e;
                if (pi < P) atomicAdd(&logits[pi], s);
            }
        }
}

__global__ void k_sigmoid(const float* __restrict__ logits, const float* __restrict__ lpb2,
                          float* __restrict__ out, int P) {
    int i = blockIdx.x * TPB + threadIdx.x;
    if (i < P) out[i] = 1.0f / (1.0f + expf(-(logits[i] + lpb2[0])));
}

// ---------------- launcher ----------------

extern "C" void kernel_launch(void* const* d_in, const int* in_sizes, int n_in,
                              void* d_out, int out_size, void* d_ws, size_t ws_size,
                              hipStream_t stream) {
    const float* x    = (const float*)d_in[0];
    const int*   ei   = (const int*)d_in[1];
    const int*   ep   = (const int*)d_in[2];
    const float* W1   = (const float*)d_in[3];
    const float* b1   = (const float*)d_in[4];
    const float* W2   = (const float*)d_in[5];
    const float* b2   = (const float*)d_in[6];
    const float* lpW1 = (const float*)d_in[7];
    const float* lpb1 = (const float*)d_in[8];
    const float* lpW2 = (const float*)d_in[9];
    const float* lpb2 = (const float*)d_in[10];

    const int n = in_sizes[0] / 512;
    const int E = in_sizes[1] / 2;
    const int P = in_sizes[2] / 2;
    const int* src = ei;
    const int* dst = ei + E;

    char* w = (char*)d_ws;
    size_t off = 0;
    auto alloc = [&](size_t bytes) {
        void* p = w + off;
        off = (off + bytes + 255) & ~(size_t)255;
        return p;
    };
    int*   cnt       = (int*)alloc((size_t)n * 4);
    int*   row_start = (int*)alloc((size_t)(n + 1) * 4);
    int*   cursor    = (int*)alloc((size_t)n * 4);
    int*   csr_src   = (int*)alloc((size_t)E * 4);
    float* csr_nrm   = (float*)alloc((size_t)E * 4);
    float* dis       = (float*)alloc((size_t)n * 4);
    float* logits    = (float*)alloc((size_t)P * 4);
    unsigned short* w1t   = (unsigned short*)alloc((size_t)512 * 512 * 2);
    unsigned short* w2t   = (unsigned short*)alloc((size_t)512 * 512 * 2);
    unsigned short* lpw1t = (unsigned short*)alloc((size_t)512 * 1024 * 2);
    unsigned short* xbf   = (unsigned short*)alloc((size_t)n * 512 * 2);  // also z_bf
    float* xw        = (float*)alloc((size_t)n * 512 * 4);
    unsigned short* zbf = xbf;   // alias: x_bf consumed by GEMM1 before z1_bf written

    dim3 blk(TPB);
    const int nb_n = (n + TPB - 1) / TPB;
    const int nb_E = (E + TPB - 1) / TPB;

    // CSR build + norms
    k_zero_int<<<nb_n, blk, 0, stream>>>(cnt, n);
    k_hist<<<nb_E, blk, 0, stream>>>(dst, cnt, E);
    k_scan<<<1, 1024, 0, stream>>>(cnt, row_start, cursor, n);
    k_dis<<<nb_n, blk, 0, stream>>>(cnt, dis, n);
    k_fill_csr<<<nb_E, blk, 0, stream>>>(src, dst, dis, cursor, csr_src, csr_nrm, E);

    // conversions
    k_f2bf<<<(n * 64 + TPB - 1) / TPB, blk, 0, stream>>>(x, xbf, n * 64);
    k_cvtT<<<(512 * 512 + TPB - 1) / TPB, blk, 0, stream>>>(W1, w1t, 512, 512);
    k_cvtT<<<(512 * 512 + TPB - 1) / TPB, blk, 0, stream>>>(W2, w2t, 512, 512);
    k_cvtT<<<(1024 * 512 + TPB - 1) / TPB, blk, 0, stream>>>(lpW1, lpw1t, 1024, 512);

    const int gy = (n + 127) / 128;
    const int agg_blocks = (n * 64 + TPB - 1) / TPB;

    // layer 1
    k_gemm_bf<<<dim3(4, gy), blk, 0, stream>>>(xbf, w1t, xw, n, 512, 512);
    k_agg_gather<<<agg_blocks, blk, 0, stream>>>(xw, row_start, csr_src, csr_nrm,
                                                 dis, b1, zbf, n, 1);
    // layer 2
    k_gemm_bf<<<dim3(4, gy), blk, 0, stream>>>(zbf, w2t, xw, n, 512, 512);
    k_agg_gather<<<agg_blocks, blk, 0, stream>>>(xw, row_start, csr_src, csr_nrm,
                                                 dis, b2, zbf, n, 0);

    // link predictor
    k_fill0<<<(P + TPB - 1) / TPB, blk, 0, stream>>>(logits, P);
    k_lp_mfma<<<dim3(4, (P + 127) / 128), blk, 0, stream>>>(zbf, ep, P, lpw1t, lpb1, lpW2, logits);
    k_sigmoid<<<(P + TPB - 1) / TPB, blk, 0, stream>>>(logits, lpb2, (float*)d_out, P);
}

// Round 4
// 729.066 us; speedup vs baseline: 11.8870x; 1.1968x over previous
//
#include <hip/hip_runtime.h>
#include <math.h>

#define TPB 256

typedef __attribute__((ext_vector_type(8))) short bf16x8;
typedef __attribute__((ext_vector_type(4))) float f32x4;

__device__ __forceinline__ unsigned cvt_bf(float f) {
    unsigned u = __float_as_uint(f);
    u += 0x7fffu + ((u >> 16) & 1u);   // round-to-nearest-even
    return u >> 16;
}
__device__ __forceinline__ unsigned pack2(float a, float b) {
    return cvt_bf(a) | (cvt_bf(b) << 16);
}

// async global->LDS, 16B per lane; LDS dest = wave-uniform base + lane*16
__device__ __forceinline__ void gload16(const void* g, void* l) {
    __builtin_amdgcn_global_load_lds(
        (const __attribute__((address_space(1))) void*)g,
        (__attribute__((address_space(3))) void*)l, 16, 0, 0);
}

// ---------------- degree / CSR build ----------------

__global__ void k_zero_int(int* p, int n) {
    int i = blockIdx.x * TPB + threadIdx.x;
    if (i < n) p[i] = 0;
}

__global__ void k_hist(const int* __restrict__ dst, int* __restrict__ cnt, int E) {
    int e = blockIdx.x * TPB + threadIdx.x;
    if (e < E) atomicAdd(&cnt[dst[e]], 1);
}

__global__ __launch_bounds__(1024)
void k_scan(const int* __restrict__ cnt, int* __restrict__ row_start,
            int* __restrict__ cursor, int n) {
    __shared__ int sums[1024];
    const int t = threadIdx.x;
    const int chunk = (n + 1023) / 1024;
    const int beg = t * chunk;
    const int end = min(beg + chunk, n);
    int s = 0;
    for (int i = beg; i < end; ++i) s += cnt[i];
    sums[t] = s;
    __syncthreads();
    for (int d = 1; d < 1024; d <<= 1) {
        int v = (t >= d) ? sums[t - d] : 0;
        __syncthreads();
        sums[t] += v;
        __syncthreads();
    }
    int excl = (t == 0) ? 0 : sums[t - 1];
    for (int i = beg; i < end; ++i) {
        row_start[i] = excl;
        cursor[i] = excl;
        excl += cnt[i];
    }
    if (t == 1023) row_start[n] = sums[1023];
}

__global__ void k_dis(const int* __restrict__ cnt, float* __restrict__ dis, int n) {
    int i = blockIdx.x * TPB + threadIdx.x;
    if (i < n) dis[i] = rsqrtf((float)cnt[i] + 1.0f);
}

__global__ void k_fill_csr(const int* __restrict__ src, const int* __restrict__ dst,
                           const float* __restrict__ dis, int* __restrict__ cursor,
                           int* __restrict__ csr_src, float* __restrict__ csr_nrm, int E) {
    int e = blockIdx.x * TPB + threadIdx.x;
    if (e >= E) return;
    int s = src[e], d = dst[e];
    int pos = atomicAdd(&cursor[d], 1);
    csr_src[pos] = s;
    csr_nrm[pos] = dis[s] * dis[d];
}

// ---------------- conversions ----------------

__global__ void k_f2bf(const float* __restrict__ in, unsigned short* __restrict__ out, int total8) {
    int i = blockIdx.x * TPB + threadIdx.x;
    if (i >= total8) return;
    float4 f0 = *(const float4*)(in + (size_t)i * 8);
    float4 f1 = *(const float4*)(in + (size_t)i * 8 + 4);
    uint4 o;
    o.x = pack2(f0.x, f0.y); o.y = pack2(f0.z, f0.w);
    o.z = pack2(f1.x, f1.y); o.w = pack2(f1.z, f1.w);
    *(uint4*)(out + (size_t)i * 8) = o;
}

// out[n][k] = bf16(in[k][n])
__global__ void k_cvtT(const float* __restrict__ in, unsigned short* __restrict__ out, int K, int N) {
    int id = blockIdx.x * TPB + threadIdx.x;
    if (id >= K * N) return;
    int k = id / N, nn = id % N;
    out[(size_t)nn * K + k] = (unsigned short)cvt_bf(in[id]);
}

// ---------------- CSR gather aggregation (bf16 in, bf16 out) ----------------
// y[v] = sum_{e: dst=v} x[src_e]*nrm_e + x[v]*dis[v]^2   (no bias, no relu)
// one wave per node; lane handles 8 bf16 (one uint4).

__global__ __launch_bounds__(256)
void k_agg_bf(const unsigned short* __restrict__ xin, const int* __restrict__ row_start,
              const int* __restrict__ csr_src, const float* __restrict__ csr_nrm,
              const float* __restrict__ dis, unsigned short* __restrict__ out, int n) {
    const int v = (blockIdx.x * TPB + threadIdx.x) >> 6;
    if (v >= n) return;
    const int lane = threadIdx.x & 63;
    const uint4* base = (const uint4*)xin;   // row stride = 64 uint4

    float d = dis[v]; float d2 = d * d;
    float acc[8];
    {
        uint4 u = base[(size_t)v * 64 + lane];
        acc[0] = d2 * __uint_as_float(u.x << 16);
        acc[1] = d2 * __uint_as_float(u.x & 0xffff0000u);
        acc[2] = d2 * __uint_as_float(u.y << 16);
        acc[3] = d2 * __uint_as_float(u.y & 0xffff0000u);
        acc[4] = d2 * __uint_as_float(u.z << 16);
        acc[5] = d2 * __uint_as_float(u.z & 0xffff0000u);
        acc[6] = d2 * __uint_as_float(u.w << 16);
        acc[7] = d2 * __uint_as_float(u.w & 0xffff0000u);
    }
    const int beg = row_start[v], end = row_start[v + 1];
    for (int j = beg; j < end; ++j) {
        int s = csr_src[j];
        float r = csr_nrm[j];
        uint4 u = base[(size_t)s * 64 + lane];
        acc[0] = fmaf(__uint_as_float(u.x << 16), r, acc[0]);
        acc[1] = fmaf(__uint_as_float(u.x & 0xffff0000u), r, acc[1]);
        acc[2] = fmaf(__uint_as_float(u.y << 16), r, acc[2]);
        acc[3] = fmaf(__uint_as_float(u.y & 0xffff0000u), r, acc[3]);
        acc[4] = fmaf(__uint_as_float(u.z << 16), r, acc[4]);
        acc[5] = fmaf(__uint_as_float(u.z & 0xffff0000u), r, acc[5]);
        acc[6] = fmaf(__uint_as_float(u.w << 16), r, acc[6]);
        acc[7] = fmaf(__uint_as_float(u.w & 0xffff0000u), r, acc[7]);
    }
    uint4 o;
    o.x = pack2(acc[0], acc[1]); o.y = pack2(acc[2], acc[3]);
    o.z = pack2(acc[4], acc[5]); o.w = pack2(acc[6], acc[7]);
    ((uint4*)out)[(size_t)v * 64 + lane] = o;
}

// ---------------- bf16 MFMA GEMM with fused bias(+relu), bf16 out ----------------
// C[M,512] = bf16( act( A[M,K] @ Bt[512,K]^T + bias ) )
// 128x128 tile, BK=32, 4 waves. Staging via global_load_lds(16B) with
// pre-swizzled source columns; fragment reads XOR the same swizzle.

__global__ __launch_bounds__(256)
void k_gemm_bf(const unsigned short* __restrict__ A, const unsigned short* __restrict__ Bt,
               const float* __restrict__ bias, unsigned short* __restrict__ C,
               int M, int K, int do_relu) {
    __shared__ __align__(16) char Asl[128 * 64];
    __shared__ __align__(16) char Bsl[128 * 64];
    const int t = threadIdx.x;
    const int m0 = blockIdx.y * 128, n0 = blockIdx.x * 128;
    const int wid = t >> 6, l = t & 63;
    const int wr = (wid >> 1) * 64, wc = (wid & 1) * 64;
    const int lrow = l & 15, g = l >> 4;

    // staging geometry: wave stages rows wid*32 .. wid*32+31 (2 loads of 16 rows)
    const int srow = (l >> 2);                   // 0..15 within 16-row group
    const int cb_src = ((l & 3) * 16) ^ ((srow & 3) << 4);   // pre-swizzled col byte
    const int r0 = wid * 32 + srow, r1 = r0 + 16;
    const size_t rowA0 = (size_t)min(m0 + r0, M - 1) * K * 2;
    const size_t rowA1 = (size_t)min(m0 + r1, M - 1) * K * 2;
    const size_t rowB0 = (size_t)(n0 + r0) * K * 2;
    const size_t rowB1 = (size_t)(n0 + r1) * K * 2;
    const char* Ab = (const char*)A;
    const char* Bb = (const char*)Bt;
    char* ldsA0 = Asl + (wid * 32) * 64;
    char* ldsA1 = ldsA0 + 16 * 64;
    char* ldsB0 = Bsl + (wid * 32) * 64;
    char* ldsB1 = ldsB0 + 16 * 64;

    f32x4 acc[4][4] = {};
    for (int k0 = 0; k0 < K; k0 += 32) {
        const size_t koff = (size_t)k0 * 2 + cb_src;
        gload16(Ab + rowA0 + koff, ldsA0);
        gload16(Ab + rowA1 + koff, ldsA1);
        gload16(Bb + rowB0 + koff, ldsB0);
        gload16(Bb + rowB1 + koff, ldsB1);
        __syncthreads();
        bf16x8 af[4], bfr[4];
#pragma unroll
        for (int i = 0; i < 4; ++i)
            af[i] = *(const bf16x8*)(Asl + (wr + i * 16 + lrow) * 64 + ((g * 16) ^ ((lrow & 3) << 4)));
#pragma unroll
        for (int j = 0; j < 4; ++j)
            bfr[j] = *(const bf16x8*)(Bsl + (wc + j * 16 + lrow) * 64 + ((g * 16) ^ ((lrow & 3) << 4)));
#pragma unroll
        for (int i = 0; i < 4; ++i)
#pragma unroll
            for (int j = 0; j < 4; ++j)
                acc[i][j] = __builtin_amdgcn_mfma_f32_16x16x32_bf16(af[i], bfr[j], acc[i][j], 0, 0, 0);
        __syncthreads();
    }
    float bv[4];
#pragma unroll
    for (int j = 0; j < 4; ++j) bv[j] = bias[n0 + wc + j * 16 + lrow];
#pragma unroll
    for (int i = 0; i < 4; ++i) {
        const int rb = m0 + wr + i * 16 + g * 4;
#pragma unroll
        for (int e = 0; e < 4; ++e) {
            const int row = rb + e;
            if (row < M) {
#pragma unroll
                for (int j = 0; j < 4; ++j) {
                    float vv = acc[i][j][e] + bv[j];
                    if (do_relu) vv = fmaxf(vv, 0.f);
                    C[(size_t)row * 512 + n0 + wc + j * 16 + lrow] = (unsigned short)cvt_bf(vv);
                }
            }
        }
    }
}

// ---------------- fused link predictor (bf16 MFMA, gathered A) ----------------

__global__ void k_fill0(float* p, int n) {
    int i = blockIdx.x * TPB + threadIdx.x;
    if (i < n) p[i] = 0.0f;
}

__global__ __launch_bounds__(256)
void k_lp_mfma(const unsigned short* __restrict__ z, const int* __restrict__ pair, int P,
               const unsigned short* __restrict__ Wt, const float* __restrict__ b1,
               const float* __restrict__ w2, float* __restrict__ logits) {
    __shared__ __align__(16) char Asl[128 * 64];
    __shared__ __align__(16) char Bsl[128 * 64];
    const int t = threadIdx.x;
    const int p0 = blockIdx.y * 128, n0 = blockIdx.x * 128;
    const int wid = t >> 6, l = t & 63;
    const int wr = (wid >> 1) * 64, wc = (wid & 1) * 64;
    const int lrow = l & 15, g = l >> 4;

    const int srow = (l >> 2);
    const int cb_src = ((l & 3) * 16) ^ ((srow & 3) << 4);
    const int r0 = wid * 32 + srow, r1 = r0 + 16;
    const int pi0 = min(p0 + r0, P - 1), pi1 = min(p0 + r1, P - 1);
    // node ids for both K-halves, per staged row
    const size_t a00 = (size_t)pair[pi0] * 1024;       // half 0 (cols 0..511)
    const size_t a01 = (size_t)pair[P + pi0] * 1024;   // half 1
    const size_t a10 = (size_t)pair[pi1] * 1024;
    const size_t a11 = (size_t)pair[P + pi1] * 1024;
    const size_t rowB0 = (size_t)(n0 + r0) * 2048;
    const size_t rowB1 = (size_t)(n0 + r1) * 2048;
    const char* zb = (const char*)z;
    const char* Wb = (const char*)Wt;
    char* ldsA0 = Asl + (wid * 32) * 64;
    char* ldsA1 = ldsA0 + 16 * 64;
    char* ldsB0 = Bsl + (wid * 32) * 64;
    char* ldsB1 = ldsB0 + 16 * 64;

    f32x4 acc[4][4] = {};
    for (int k0 = 0; k0 < 1024; k0 += 32) {
        const size_t ka = (size_t)(k0 & 511) * 2 + cb_src;
        const size_t kb = (size_t)k0 * 2 + cb_src;
        const size_t rA0 = (k0 < 512) ? a00 : a01;
        const size_t rA1 = (k0 < 512) ? a10 : a11;
        gload16(zb + rA0 + ka, ldsA0);
        gload16(zb + rA1 + ka, ldsA1);
        gload16(Wb + rowB0 + kb, ldsB0);
        gload16(Wb + rowB1 + kb, ldsB1);
        __syncthreads();
        bf16x8 af[4], bfr[4];
#pragma unroll
        for (int i = 0; i < 4; ++i)
            af[i] = *(const bf16x8*)(Asl + (wr + i * 16 + lrow) * 64 + ((g * 16) ^ ((lrow & 3) << 4)));
#pragma unroll
        for (int j = 0; j < 4; ++j)
            bfr[j] = *(const bf16x8*)(Bsl + (wc + j * 16 + lrow) * 64 + ((g * 16) ^ ((lrow & 3) << 4)));
#pragma unroll
        for (int i = 0; i < 4; ++i)
#pragma unroll
            for (int j = 0; j < 4; ++j)
                acc[i][j] = __builtin_amdgcn_mfma_f32_16x16x32_bf16(af[i], bfr[j], acc[i][j], 0, 0, 0);
        __syncthreads();
    }
    // epilogue: +b1, relu, dot w2, reduce across lrow groups
    float b1v[4], w2v[4];
#pragma unroll
    for (int j = 0; j < 4; ++j) {
        int col = n0 + wc + j * 16 + lrow;
        b1v[j] = b1[col];
        w2v[j] = w2[col];
    }
#pragma unroll
    for (int i = 0; i < 4; ++i)
#pragma unroll
        for (int e = 0; e < 4; ++e) {
            float s = 0.f;
#pragma unroll
            for (int j = 0; j < 4; ++j) {
                float h = acc[i][j][e] + b1v[j];
                h = fmaxf(h, 0.f);
                s = fmaf(h, w2v[j], s);
            }
            s += __shfl_xor(s, 1, 64);
            s += __shfl_xor(s, 2, 64);
            s += __shfl_xor(s, 4, 64);
            s += __shfl_xor(s, 8, 64);
            if (lrow == 0) {
                int pi = p0 + wr + i * 16 + g * 4 + e;
                if (pi < P) atomicAdd(&logits[pi], s);
            }
        }
}

__global__ void k_sigmoid(const float* __restrict__ logits, const float* __restrict__ lpb2,
                          float* __restrict__ out, int P) {
    int i = blockIdx.x * TPB + threadIdx.x;
    if (i < P) out[i] = 1.0f / (1.0f + expf(-(logits[i] + lpb2[0])));
}

// ---------------- launcher ----------------

extern "C" void kernel_launch(void* const* d_in, const int* in_sizes, int n_in,
                              void* d_out, int out_size, void* d_ws, size_t ws_size,
                              hipStream_t stream) {
    const float* x    = (const float*)d_in[0];
    const int*   ei   = (const int*)d_in[1];
    const int*   ep   = (const int*)d_in[2];
    const float* W1   = (const float*)d_in[3];
    const float* b1   = (const float*)d_in[4];
    const float* W2   = (const float*)d_in[5];
    const float* b2   = (const float*)d_in[6];
    const float* lpW1 = (const float*)d_in[7];
    const float* lpb1 = (const float*)d_in[8];
    const float* lpW2 = (const float*)d_in[9];
    const float* lpb2 = (const float*)d_in[10];

    const int n = in_sizes[0] / 512;
    const int E = in_sizes[1] / 2;
    const int P = in_sizes[2] / 2;
    const int* src = ei;
    const int* dst = ei + E;

    char* w = (char*)d_ws;
    size_t off = 0;
    auto alloc = [&](size_t bytes) {
        void* p = w + off;
        off = (off + bytes + 255) & ~(size_t)255;
        return p;
    };
    int*   cnt       = (int*)alloc((size_t)n * 4);
    int*   row_start = (int*)alloc((size_t)(n + 1) * 4);
    int*   cursor    = (int*)alloc((size_t)n * 4);
    int*   csr_src   = (int*)alloc((size_t)E * 4);
    float* csr_nrm   = (float*)alloc((size_t)E * 4);
    float* dis       = (float*)alloc((size_t)n * 4);
    float* logits    = (float*)alloc((size_t)P * 4);
    unsigned short* w1t   = (unsigned short*)alloc((size_t)512 * 512 * 2);
    unsigned short* w2t   = (unsigned short*)alloc((size_t)512 * 512 * 2);
    unsigned short* lpw1t = (unsigned short*)alloc((size_t)512 * 1024 * 2);
    unsigned short* bufA  = (unsigned short*)alloc((size_t)n * 512 * 2);
    unsigned short* bufB  = (unsigned short*)alloc((size_t)n * 512 * 2);

    dim3 blk(TPB);
    const int nb_n = (n + TPB - 1) / TPB;
    const int nb_E = (E + TPB - 1) / TPB;

    // CSR build + norms
    k_zero_int<<<nb_n, blk, 0, stream>>>(cnt, n);
    k_hist<<<nb_E, blk, 0, stream>>>(dst, cnt, E);
    k_scan<<<1, 1024, 0, stream>>>(cnt, row_start, cursor, n);
    k_dis<<<nb_n, blk, 0, stream>>>(cnt, dis, n);
    k_fill_csr<<<nb_E, blk, 0, stream>>>(src, dst, dis, cursor, csr_src, csr_nrm, E);

    // conversions
    k_f2bf<<<(n * 64 + TPB - 1) / TPB, blk, 0, stream>>>(x, bufA, n * 64);
    k_cvtT<<<(512 * 512 + TPB - 1) / TPB, blk, 0, stream>>>(W1, w1t, 512, 512);
    k_cvtT<<<(512 * 512 + TPB - 1) / TPB, blk, 0, stream>>>(W2, w2t, 512, 512);
    k_cvtT<<<(1024 * 512 + TPB - 1) / TPB, blk, 0, stream>>>(lpW1, lpw1t, 1024, 512);

    const int gy = (n + 127) / 128;
    const int agg_blocks = (n * 64 + TPB - 1) / TPB;

    // layer 1: y1 = A_hat x ; z1 = relu(y1 @ W1 + b1)
    k_agg_bf<<<agg_blocks, blk, 0, stream>>>(bufA, row_start, csr_src, csr_nrm, dis, bufB, n);
    k_gemm_bf<<<dim3(4, gy), blk, 0, stream>>>(bufB, w1t, b1, bufA, n, 512, 1);
    // layer 2: y2 = A_hat z1 ; z2 = y2 @ W2 + b2
    k_agg_bf<<<agg_blocks, blk, 0, stream>>>(bufA, row_start, csr_src, csr_nrm, dis, bufB, n);
    k_gemm_bf<<<dim3(4, gy), blk, 0, stream>>>(bufB, w2t, b2, bufA, n, 512, 0);

    // link predictor
    k_fill0<<<(P + TPB - 1) / TPB, blk, 0, stream>>>(logits, P);
    k_lp_mfma<<<dim3(4, (P + 127) / 128), blk, 0, stream>>>(bufA, ep, P, lpw1t, lpb1, lpW2, logits);
    k_sigmoid<<<(P + TPB - 1) / TPB, blk, 0, stream>>>(logits, lpb2, (float*)d_out, P);
}

// Round 5
// 708.133 us; speedup vs baseline: 12.2383x; 1.0296x over previous
//
#include <hip/hip_runtime.h>
#include <math.h>

#define TPB 256

typedef __attribute__((ext_vector_type(8))) short bf16x8;
typedef __attribute__((ext_vector_type(4))) float f32x4;

__device__ __forceinline__ unsigned cvt_bf(float f) {
    unsigned u = __float_as_uint(f);
    u += 0x7fffu + ((u >> 16) & 1u);   // round-to-nearest-even
    return u >> 16;
}
__device__ __forceinline__ unsigned pack2(float a, float b) {
    return cvt_bf(a) | (cvt_bf(b) << 16);
}

// async global->LDS, 16B per lane; LDS dest = wave-uniform base + lane*16
__device__ __forceinline__ void gload16(const void* g, void* l) {
    __builtin_amdgcn_global_load_lds(
        (const __attribute__((address_space(1))) void*)g,
        (__attribute__((address_space(3))) void*)l, 16, 0, 0);
}

// ---------------- degree / CSR build ----------------

__global__ void k_zero_int(int* p, int n) {
    int i = blockIdx.x * TPB + threadIdx.x;
    if (i < n) p[i] = 0;
}

__global__ void k_hist(const int* __restrict__ dst, int* __restrict__ cnt, int E) {
    int e = blockIdx.x * TPB + threadIdx.x;
    if (e < E) atomicAdd(&cnt[dst[e]], 1);
}

__global__ __launch_bounds__(1024)
void k_scan(const int* __restrict__ cnt, int* __restrict__ row_start,
            int* __restrict__ cursor, int n) {
    __shared__ int sums[1024];
    const int t = threadIdx.x;
    const int chunk = (n + 1023) / 1024;
    const int beg = t * chunk;
    const int end = min(beg + chunk, n);
    int s = 0;
    for (int i = beg; i < end; ++i) s += cnt[i];
    sums[t] = s;
    __syncthreads();
    for (int d = 1; d < 1024; d <<= 1) {
        int v = (t >= d) ? sums[t - d] : 0;
        __syncthreads();
        sums[t] += v;
        __syncthreads();
    }
    int excl = (t == 0) ? 0 : sums[t - 1];
    for (int i = beg; i < end; ++i) {
        row_start[i] = excl;
        cursor[i] = excl;
        excl += cnt[i];
    }
    if (t == 1023) row_start[n] = sums[1023];
}

__global__ void k_dis(const int* __restrict__ cnt, float* __restrict__ dis, int n) {
    int i = blockIdx.x * TPB + threadIdx.x;
    if (i < n) dis[i] = rsqrtf((float)cnt[i] + 1.0f);
}

__global__ void k_fill_csr(const int* __restrict__ src, const int* __restrict__ dst,
                           const float* __restrict__ dis, int* __restrict__ cursor,
                           int* __restrict__ csr_src, float* __restrict__ csr_nrm, int E) {
    int e = blockIdx.x * TPB + threadIdx.x;
    if (e >= E) return;
    int s = src[e], d = dst[e];
    int pos = atomicAdd(&cursor[d], 1);
    csr_src[pos] = s;
    csr_nrm[pos] = dis[s] * dis[d];
}

// ---------------- conversions ----------------

__global__ void k_f2bf(const float* __restrict__ in, unsigned short* __restrict__ out, int total8) {
    int i = blockIdx.x * TPB + threadIdx.x;
    if (i >= total8) return;
    float4 f0 = *(const float4*)(in + (size_t)i * 8);
    float4 f1 = *(const float4*)(in + (size_t)i * 8 + 4);
    uint4 o;
    o.x = pack2(f0.x, f0.y); o.y = pack2(f0.z, f0.w);
    o.z = pack2(f1.x, f1.y); o.w = pack2(f1.z, f1.w);
    *(uint4*)(out + (size_t)i * 8) = o;
}

// out[n][k] = bf16(in[k][n])
__global__ void k_cvtT(const float* __restrict__ in, unsigned short* __restrict__ out, int K, int N) {
    int id = blockIdx.x * TPB + threadIdx.x;
    if (id >= K * N) return;
    int k = id / N, nn = id % N;
    out[(size_t)nn * K + k] = (unsigned short)cvt_bf(in[id]);
}

// ---------------- CSR gather aggregation (bf16 in, bf16 out) ----------------

__global__ __launch_bounds__(256)
void k_agg_bf(const unsigned short* __restrict__ xin, const int* __restrict__ row_start,
              const int* __restrict__ csr_src, const float* __restrict__ csr_nrm,
              const float* __restrict__ dis, unsigned short* __restrict__ out, int n) {
    const int v = (blockIdx.x * TPB + threadIdx.x) >> 6;
    if (v >= n) return;
    const int lane = threadIdx.x & 63;
    const uint4* base = (const uint4*)xin;

    float d = dis[v]; float d2 = d * d;
    float acc[8];
    {
        uint4 u = base[(size_t)v * 64 + lane];
        acc[0] = d2 * __uint_as_float(u.x << 16);
        acc[1] = d2 * __uint_as_float(u.x & 0xffff0000u);
        acc[2] = d2 * __uint_as_float(u.y << 16);
        acc[3] = d2 * __uint_as_float(u.y & 0xffff0000u);
        acc[4] = d2 * __uint_as_float(u.z << 16);
        acc[5] = d2 * __uint_as_float(u.z & 0xffff0000u);
        acc[6] = d2 * __uint_as_float(u.w << 16);
        acc[7] = d2 * __uint_as_float(u.w & 0xffff0000u);
    }
    const int beg = row_start[v], end = row_start[v + 1];
    for (int j = beg; j < end; ++j) {
        int s = csr_src[j];
        float r = csr_nrm[j];
        uint4 u = base[(size_t)s * 64 + lane];
        acc[0] = fmaf(__uint_as_float(u.x << 16), r, acc[0]);
        acc[1] = fmaf(__uint_as_float(u.x & 0xffff0000u), r, acc[1]);
        acc[2] = fmaf(__uint_as_float(u.y << 16), r, acc[2]);
        acc[3] = fmaf(__uint_as_float(u.y & 0xffff0000u), r, acc[3]);
        acc[4] = fmaf(__uint_as_float(u.z << 16), r, acc[4]);
        acc[5] = fmaf(__uint_as_float(u.z & 0xffff0000u), r, acc[5]);
        acc[6] = fmaf(__uint_as_float(u.w << 16), r, acc[6]);
        acc[7] = fmaf(__uint_as_float(u.w & 0xffff0000u), r, acc[7]);
    }
    uint4 o;
    o.x = pack2(acc[0], acc[1]); o.y = pack2(acc[2], acc[3]);
    o.z = pack2(acc[4], acc[5]); o.w = pack2(acc[6], acc[7]);
    ((uint4*)out)[(size_t)v * 64 + lane] = o;
}

// ---------------- bf16 MFMA GEMM with fused bias(+relu), bf16 out ----------------
// (unchanged from R4: 128x128 tile, pre-swizzled global_load_lds staging)

__global__ __launch_bounds__(256)
void k_gemm_bf(const unsigned short* __restrict__ A, const unsigned short* __restrict__ Bt,
               const float* __restrict__ bias, unsigned short* __restrict__ C,
               int M, int K, int do_relu) {
    __shared__ __align__(16) char Asl[128 * 64];
    __shared__ __align__(16) char Bsl[128 * 64];
    const int t = threadIdx.x;
    const int m0 = blockIdx.y * 128, n0 = blockIdx.x * 128;
    const int wid = t >> 6, l = t & 63;
    const int wr = (wid >> 1) * 64, wc = (wid & 1) * 64;
    const int lrow = l & 15, g = l >> 4;

    const int srow = (l >> 2);
    const int cb_src = ((l & 3) * 16) ^ ((srow & 3) << 4);
    const int r0 = wid * 32 + srow, r1 = r0 + 16;
    const size_t rowA0 = (size_t)min(m0 + r0, M - 1) * K * 2;
    const size_t rowA1 = (size_t)min(m0 + r1, M - 1) * K * 2;
    const size_t rowB0 = (size_t)(n0 + r0) * K * 2;
    const size_t rowB1 = (size_t)(n0 + r1) * K * 2;
    const char* Ab = (const char*)A;
    const char* Bb = (const char*)Bt;
    char* ldsA0 = Asl + (wid * 32) * 64;
    char* ldsA1 = ldsA0 + 16 * 64;
    char* ldsB0 = Bsl + (wid * 32) * 64;
    char* ldsB1 = ldsB0 + 16 * 64;

    f32x4 acc[4][4] = {};
    for (int k0 = 0; k0 < K; k0 += 32) {
        const size_t koff = (size_t)k0 * 2 + cb_src;
        gload16(Ab + rowA0 + koff, ldsA0);
        gload16(Ab + rowA1 + koff, ldsA1);
        gload16(Bb + rowB0 + koff, ldsB0);
        gload16(Bb + rowB1 + koff, ldsB1);
        __syncthreads();
        bf16x8 af[4], bfr[4];
#pragma unroll
        for (int i = 0; i < 4; ++i)
            af[i] = *(const bf16x8*)(Asl + (wr + i * 16 + lrow) * 64 + ((g * 16) ^ ((lrow & 3) << 4)));
#pragma unroll
        for (int j = 0; j < 4; ++j)
            bfr[j] = *(const bf16x8*)(Bsl + (wc + j * 16 + lrow) * 64 + ((g * 16) ^ ((lrow & 3) << 4)));
#pragma unroll
        for (int i = 0; i < 4; ++i)
#pragma unroll
            for (int j = 0; j < 4; ++j)
                acc[i][j] = __builtin_amdgcn_mfma_f32_16x16x32_bf16(af[i], bfr[j], acc[i][j], 0, 0, 0);
        __syncthreads();
    }
    float bv[4];
#pragma unroll
    for (int j = 0; j < 4; ++j) bv[j] = bias[n0 + wc + j * 16 + lrow];
#pragma unroll
    for (int i = 0; i < 4; ++i) {
        const int rb = m0 + wr + i * 16 + g * 4;
#pragma unroll
        for (int e = 0; e < 4; ++e) {
            const int row = rb + e;
            if (row < M) {
#pragma unroll
                for (int j = 0; j < 4; ++j) {
                    float vv = acc[i][j][e] + bv[j];
                    if (do_relu) vv = fmaxf(vv, 0.f);
                    C[(size_t)row * 512 + n0 + wc + j * 16 + lrow] = (unsigned short)cvt_bf(vv);
                }
            }
        }
    }
}

// ---------------- link predictor: 256x256 tile, 8 waves, tri-buffered ----------------
// counted-vmcnt pipeline (prefetch distance 2), raw s_barrier, conflict-free
// subtile LDS layout [kslot16B][row][16B].

__global__ void k_fill0(float* p, int n) {
    int i = blockIdx.x * TPB + threadIdx.x;
    if (i < n) p[i] = 0.0f;
}

__global__ __launch_bounds__(512, 2)
void k_lp8(const unsigned short* __restrict__ z, const int* __restrict__ pair, int P,
           const unsigned short* __restrict__ Wt, const float* __restrict__ b1,
           const float* __restrict__ w2, float* __restrict__ logits) {
    extern __shared__ __align__(16) char lds[];   // 3*16KB A + 3*16KB B = 96KB
    char* ldsA = lds;
    char* ldsB = lds + 3 * 16384;

    const int t = threadIdx.x;
    const int wid = t >> 6, l = t & 63;
    const int wm = wid >> 2, wn = wid & 3;
    const int lrow = l & 15, g = l >> 4;
    const int p0 = blockIdx.y * 256;
    const int n0 = blockIdx.x;            // col base n0*256

    // staging: wave wid owns subtiles {2wid, 2wid+1} of both A and B.
    const int sr = l & 15, sc = l >> 4;
    const int prow0 = min(p0 + wid * 32 + sr, P - 1);
    const int prow1 = min(p0 + wid * 32 + 16 + sr, P - 1);
    const char* zb = (const char*)z;
    const char* Wb = (const char*)Wt;
    const size_t a00 = (size_t)pair[prow0] * 1024 + sc * 16;       // row0, half0
    const size_t a01 = (size_t)pair[P + prow0] * 1024 + sc * 16;   // row0, half1
    const size_t a10 = (size_t)pair[prow1] * 1024 + sc * 16;
    const size_t a11 = (size_t)pair[P + prow1] * 1024 + sc * 16;
    const size_t bb0 = (size_t)(n0 * 256 + wid * 32 + sr) * 2048 + sc * 16;
    const size_t bb1 = bb0 + (size_t)16 * 2048;

    f32x4 acc[8][4] = {};

#define STAGE(tt, q) do {                                                     \
        const int _b = (tt) % 3;                                              \
        if ((q) == 0) gload16(zb + (((tt) >= 16) ? a01 : a00) + ((tt) & 15) * 64, \
                              ldsA + _b * 16384 + (2 * wid) * 1024);          \
        if ((q) == 1) gload16(zb + (((tt) >= 16) ? a11 : a10) + ((tt) & 15) * 64, \
                              ldsA + _b * 16384 + (2 * wid + 1) * 1024);      \
        if ((q) == 2) gload16(Wb + bb0 + (size_t)(tt) * 64,                   \
                              ldsB + _b * 16384 + (2 * wid) * 1024);          \
        if ((q) == 3) gload16(Wb + bb1 + (size_t)(tt) * 64,                   \
                              ldsB + _b * 16384 + (2 * wid + 1) * 1024);      \
    } while (0)

    // prologue: tiles 0 and 1
#pragma unroll
    for (int q = 0; q < 4; ++q) STAGE(0, q);
#pragma unroll
    for (int q = 0; q < 4; ++q) STAGE(1, q);
    asm volatile("s_waitcnt vmcnt(4)" ::: "memory");   // tile 0 complete
    __builtin_amdgcn_s_barrier();
    __builtin_amdgcn_sched_barrier(0);

    for (int tt = 0; tt < 32; ++tt) {
        const char* Ab = ldsA + (tt % 3) * 16384 + (wm * 8) * 1024 + g * 256 + lrow * 16;
        const char* Bb2 = ldsB + (tt % 3) * 16384 + (wn * 4) * 1024 + g * 256 + lrow * 16;
        const bool pf = (tt + 2 < 32);
#pragma unroll
        for (int q = 0; q < 4; ++q) {
            if (pf) STAGE(tt + 2, q);
            const int mb = (q >> 1) * 4, nb = (q & 1) * 2;
            bf16x8 af[4], bfr[2];
#pragma unroll
            for (int i = 0; i < 4; ++i)
                af[i] = *(const bf16x8*)(Ab + (mb + i) * 1024);
#pragma unroll
            for (int j = 0; j < 2; ++j)
                bfr[j] = *(const bf16x8*)(Bb2 + (nb + j) * 1024);
            __builtin_amdgcn_s_setprio(1);
#pragma unroll
            for (int i = 0; i < 4; ++i)
#pragma unroll
                for (int j = 0; j < 2; ++j)
                    acc[mb + i][nb + j] = __builtin_amdgcn_mfma_f32_16x16x32_bf16(
                        af[i], bfr[j], acc[mb + i][nb + j], 0, 0, 0);
            __builtin_amdgcn_s_setprio(0);
        }
        // boundary: ensure tile tt+1 complete everywhere; keep tile tt+2 in flight
        if (pf) asm volatile("s_waitcnt vmcnt(4)" ::: "memory");
        else    asm volatile("s_waitcnt vmcnt(0)" ::: "memory");
        __builtin_amdgcn_s_barrier();
        __builtin_amdgcn_sched_barrier(0);
    }
#undef STAGE

    // epilogue: +b1, relu, dot w2, reduce across the 16 lrow lanes
    float b1v[4], w2v[4];
#pragma unroll
    for (int j = 0; j < 4; ++j) {
        int col = n0 * 256 + wn * 64 + j * 16 + lrow;
        b1v[j] = b1[col];
        w2v[j] = w2[col];
    }
#pragma unroll
    for (int i = 0; i < 8; ++i)
#pragma unroll
        for (int e = 0; e < 4; ++e) {
            float s = 0.f;
#pragma unroll
            for (int j = 0; j < 4; ++j) {
                float h = acc[i][j][e] + b1v[j];
                h = fmaxf(h, 0.f);
                s = fmaf(h, w2v[j], s);
            }
            s += __shfl_xor(s, 1, 64);
            s += __shfl_xor(s, 2, 64);
            s += __shfl_xor(s, 4, 64);
            s += __shfl_xor(s, 8, 64);
            if (lrow == 0) {
                int pi = p0 + wm * 128 + i * 16 + g * 4 + e;
                if (pi < P) atomicAdd(&logits[pi], s);
            }
        }
}

__global__ void k_sigmoid(const float* __restrict__ logits, const float* __restrict__ lpb2,
                          float* __restrict__ out, int P) {
    int i = blockIdx.x * TPB + threadIdx.x;
    if (i < P) out[i] = 1.0f / (1.0f + expf(-(logits[i] + lpb2[0])));
}

// ---------------- launcher ----------------

extern "C" void kernel_launch(void* const* d_in, const int* in_sizes, int n_in,
                              void* d_out, int out_size, void* d_ws, size_t ws_size,
                              hipStream_t stream) {
    const float* x    = (const float*)d_in[0];
    const int*   ei   = (const int*)d_in[1];
    const int*   ep   = (const int*)d_in[2];
    const float* W1   = (const float*)d_in[3];
    const float* b1   = (const float*)d_in[4];
    const float* W2   = (const float*)d_in[5];
    const float* b2   = (const float*)d_in[6];
    const float* lpW1 = (const float*)d_in[7];
    const float* lpb1 = (const float*)d_in[8];
    const float* lpW2 = (const float*)d_in[9];
    const float* lpb2 = (const float*)d_in[10];

    const int n = in_sizes[0] / 512;
    const int E = in_sizes[1] / 2;
    const int P = in_sizes[2] / 2;
    const int* src = ei;
    const int* dst = ei + E;

    char* w = (char*)d_ws;
    size_t off = 0;
    auto alloc = [&](size_t bytes) {
        void* p = w + off;
        off = (off + bytes + 255) & ~(size_t)255;
        return p;
    };
    int*   cnt       = (int*)alloc((size_t)n * 4);
    int*   row_start = (int*)alloc((size_t)(n + 1) * 4);
    int*   cursor    = (int*)alloc((size_t)n * 4);
    int*   csr_src   = (int*)alloc((size_t)E * 4);
    float* csr_nrm   = (float*)alloc((size_t)E * 4);
    float* dis       = (float*)alloc((size_t)n * 4);
    float* logits    = (float*)alloc((size_t)P * 4);
    unsigned short* w1t   = (unsigned short*)alloc((size_t)512 * 512 * 2);
    unsigned short* w2t   = (unsigned short*)alloc((size_t)512 * 512 * 2);
    unsigned short* lpw1t = (unsigned short*)alloc((size_t)512 * 1024 * 2);
    unsigned short* bufA  = (unsigned short*)alloc((size_t)n * 512 * 2);
    unsigned short* bufB  = (unsigned short*)alloc((size_t)n * 512 * 2);

    dim3 blk(TPB);
    const int nb_n = (n + TPB - 1) / TPB;
    const int nb_E = (E + TPB - 1) / TPB;

    // CSR build + norms
    k_zero_int<<<nb_n, blk, 0, stream>>>(cnt, n);
    k_hist<<<nb_E, blk, 0, stream>>>(dst, cnt, E);
    k_scan<<<1, 1024, 0, stream>>>(cnt, row_start, cursor, n);
    k_dis<<<nb_n, blk, 0, stream>>>(cnt, dis, n);
    k_fill_csr<<<nb_E, blk, 0, stream>>>(src, dst, dis, cursor, csr_src, csr_nrm, E);

    // conversions
    k_f2bf<<<(n * 64 + TPB - 1) / TPB, blk, 0, stream>>>(x, bufA, n * 64);
    k_cvtT<<<(512 * 512 + TPB - 1) / TPB, blk, 0, stream>>>(W1, w1t, 512, 512);
    k_cvtT<<<(512 * 512 + TPB - 1) / TPB, blk, 0, stream>>>(W2, w2t, 512, 512);
    k_cvtT<<<(1024 * 512 + TPB - 1) / TPB, blk, 0, stream>>>(lpW1, lpw1t, 1024, 512);

    const int gy = (n + 127) / 128;
    const int agg_blocks = (n * 64 + TPB - 1) / TPB;

    // layer 1: y1 = A_hat x ; z1 = relu(y1 @ W1 + b1)
    k_agg_bf<<<agg_blocks, blk, 0, stream>>>(bufA, row_start, csr_src, csr_nrm, dis, bufB, n);
    k_gemm_bf<<<dim3(4, gy), blk, 0, stream>>>(bufB, w1t, b1, bufA, n, 512, 1);
    // layer 2: y2 = A_hat z1 ; z2 = y2 @ W2 + b2
    k_agg_bf<<<agg_blocks, blk, 0, stream>>>(bufA, row_start, csr_src, csr_nrm, dis, bufB, n);
    k_gemm_bf<<<dim3(4, gy), blk, 0, stream>>>(bufB, w2t, b2, bufA, n, 512, 0);

    // link predictor (256x256 tile, tri-buffered counted-vmcnt pipeline)
    k_fill0<<<(P + TPB - 1) / TPB, blk, 0, stream>>>(logits, P);
    k_lp8<<<dim3(2, (P + 255) / 256), dim3(512), 98304, stream>>>(bufA, ep, P, lpw1t, lpb1, lpW2, logits);
    k_sigmoid<<<(P + TPB - 1) / TPB, blk, 0, stream>>>(logits, lpb2, (float*)d_out, P);
}

// Round 6
// 575.376 us; speedup vs baseline: 15.0621x; 1.2307x over previous
//
#include <hip/hip_runtime.h>
#include <math.h>

#define TPB 256

typedef __attribute__((ext_vector_type(8))) short bf16x8;
typedef __attribute__((ext_vector_type(4))) float f32x4;

__device__ __forceinline__ unsigned cvt_bf(float f) {
    unsigned u = __float_as_uint(f);
    u += 0x7fffu + ((u >> 16) & 1u);   // round-to-nearest-even
    return u >> 16;
}
__device__ __forceinline__ unsigned pack2(float a, float b) {
    return cvt_bf(a) | (cvt_bf(b) << 16);
}

// async global->LDS, 16B per lane; LDS dest = wave-uniform base + lane*16
__device__ __forceinline__ void gload16(const void* g, void* l) {
    __builtin_amdgcn_global_load_lds(
        (const __attribute__((address_space(1))) void*)g,
        (__attribute__((address_space(3))) void*)l, 16, 0, 0);
}

// ---------------- degree / CSR build ----------------

__global__ void k_zero_int(int* p, int n) {
    int i = blockIdx.x * TPB + threadIdx.x;
    if (i < n) p[i] = 0;
}

__global__ void k_hist(const int* __restrict__ dst, int* __restrict__ cnt, int E) {
    int e = blockIdx.x * TPB + threadIdx.x;
    if (e < E) atomicAdd(&cnt[dst[e]], 1);
}

__global__ __launch_bounds__(1024)
void k_scan(const int* __restrict__ cnt, int* __restrict__ row_start,
            int* __restrict__ cursor, int n) {
    __shared__ int sums[1024];
    const int t = threadIdx.x;
    const int chunk = (n + 1023) / 1024;
    const int beg = t * chunk;
    const int end = min(beg + chunk, n);
    int s = 0;
    for (int i = beg; i < end; ++i) s += cnt[i];
    sums[t] = s;
    __syncthreads();
    for (int d = 1; d < 1024; d <<= 1) {
        int v = (t >= d) ? sums[t - d] : 0;
        __syncthreads();
        sums[t] += v;
        __syncthreads();
    }
    int excl = (t == 0) ? 0 : sums[t - 1];
    for (int i = beg; i < end; ++i) {
        row_start[i] = excl;
        cursor[i] = excl;
        excl += cnt[i];
    }
    if (t == 1023) row_start[n] = sums[1023];
}

__global__ void k_dis(const int* __restrict__ cnt, float* __restrict__ dis, int n) {
    int i = blockIdx.x * TPB + threadIdx.x;
    if (i < n) dis[i] = rsqrtf((float)cnt[i] + 1.0f);
}

__global__ void k_fill_csr(const int* __restrict__ src, const int* __restrict__ dst,
                           const float* __restrict__ dis, int* __restrict__ cursor,
                           int* __restrict__ csr_src, float* __restrict__ csr_nrm, int E) {
    int e = blockIdx.x * TPB + threadIdx.x;
    if (e >= E) return;
    int s = src[e], d = dst[e];
    int pos = atomicAdd(&cursor[d], 1);
    csr_src[pos] = s;
    csr_nrm[pos] = dis[s] * dis[d];
}

// ---------------- conversions ----------------

__global__ void k_f2bf(const float* __restrict__ in, unsigned short* __restrict__ out, int total8) {
    int i = blockIdx.x * TPB + threadIdx.x;
    if (i >= total8) return;
    float4 f0 = *(const float4*)(in + (size_t)i * 8);
    float4 f1 = *(const float4*)(in + (size_t)i * 8 + 4);
    uint4 o;
    o.x = pack2(f0.x, f0.y); o.y = pack2(f0.z, f0.w);
    o.z = pack2(f1.x, f1.y); o.w = pack2(f1.z, f1.w);
    *(uint4*)(out + (size_t)i * 8) = o;
}

// out[n][k] = bf16(in[k][n])   (in: [K,N] row-major)
__global__ void k_cvtT(const float* __restrict__ in, unsigned short* __restrict__ out, int K, int N) {
    int id = blockIdx.x * TPB + threadIdx.x;
    if (id >= K * N) return;
    int k = id / N, nn = id % N;
    out[(size_t)nn * K + k] = (unsigned short)cvt_bf(in[id]);
}

// lpW1 [1024,512] -> out [1024,512] Bt-ext layout:
// out[j][k] = (j<512) ? lpW1[k][j] : lpW1[512+k][j-512]
__global__ void k_cvtT_lp(const float* __restrict__ in, unsigned short* __restrict__ out) {
    int id = blockIdx.x * TPB + threadIdx.x;
    if (id >= 1024 * 512) return;
    int j = id >> 9, k = id & 511;
    float v = (j < 512) ? in[(size_t)k * 512 + j] : in[(size_t)(512 + k) * 512 + (j - 512)];
    out[id] = (unsigned short)cvt_bf(v);
}

// bias_big[j] = (j<512 ? lpb1[j] : 0) + sum_k b2[k]*lpW1ext[k][j]
__global__ void k_bias_lp(const float* __restrict__ lpW1, const float* __restrict__ b2,
                          const float* __restrict__ lpb1, float* __restrict__ bias_big) {
    int j = blockIdx.x * TPB + threadIdx.x;
    if (j >= 1024) return;
    float s = (j < 512) ? lpb1[j] : 0.f;
    const int col = (j < 512) ? j : (j - 512);
    const int ro = (j < 512) ? 0 : 512;
    for (int k = 0; k < 512; ++k)
        s = fmaf(b2[k], lpW1[(size_t)(ro + k) * 512 + col], s);
    bias_big[j] = s;
}

__global__ void k_fill0(float* p, int n) {
    int i = blockIdx.x * TPB + threadIdx.x;
    if (i < n) p[i] = 0.0f;
}

// ---------------- CSR gather aggregation (bf16 in, bf16 out) ----------------

__global__ __launch_bounds__(256)
void k_agg_bf(const unsigned short* __restrict__ xin, const int* __restrict__ row_start,
              const int* __restrict__ csr_src, const float* __restrict__ csr_nrm,
              const float* __restrict__ dis, unsigned short* __restrict__ out, int n) {
    const int v = (blockIdx.x * TPB + threadIdx.x) >> 6;
    if (v >= n) return;
    const int lane = threadIdx.x & 63;
    const uint4* base = (const uint4*)xin;

    float d = dis[v]; float d2 = d * d;
    float acc[8];
    {
        uint4 u = base[(size_t)v * 64 + lane];
        acc[0] = d2 * __uint_as_float(u.x << 16);
        acc[1] = d2 * __uint_as_float(u.x & 0xffff0000u);
        acc[2] = d2 * __uint_as_float(u.y << 16);
        acc[3] = d2 * __uint_as_float(u.y & 0xffff0000u);
        acc[4] = d2 * __uint_as_float(u.z << 16);
        acc[5] = d2 * __uint_as_float(u.z & 0xffff0000u);
        acc[6] = d2 * __uint_as_float(u.w << 16);
        acc[7] = d2 * __uint_as_float(u.w & 0xffff0000u);
    }
    const int beg = row_start[v], end = row_start[v + 1];
    for (int j = beg; j < end; ++j) {
        int s = csr_src[j];
        float r = csr_nrm[j];
        uint4 u = base[(size_t)s * 64 + lane];
        acc[0] = fmaf(__uint_as_float(u.x << 16), r, acc[0]);
        acc[1] = fmaf(__uint_as_float(u.x & 0xffff0000u), r, acc[1]);
        acc[2] = fmaf(__uint_as_float(u.y << 16), r, acc[2]);
        acc[3] = fmaf(__uint_as_float(u.y & 0xffff0000u), r, acc[3]);
        acc[4] = fmaf(__uint_as_float(u.z << 16), r, acc[4]);
        acc[5] = fmaf(__uint_as_float(u.z & 0xffff0000u), r, acc[5]);
        acc[6] = fmaf(__uint_as_float(u.w << 16), r, acc[6]);
        acc[7] = fmaf(__uint_as_float(u.w & 0xffff0000u), r, acc[7]);
    }
    uint4 o;
    o.x = pack2(acc[0], acc[1]); o.y = pack2(acc[2], acc[3]);
    o.z = pack2(acc[4], acc[5]); o.w = pack2(acc[6], acc[7]);
    ((uint4*)out)[(size_t)v * 64 + lane] = o;
}

// ---------------- bf16 MFMA GEMM with fused bias(+relu), bf16 out ----------------
// C[M,N] = bf16( act( A[M,K] @ Bt[N,K]^T + bias ) )
// 128x128 tile, BK=32, 4 waves, pre-swizzled global_load_lds staging.

__global__ __launch_bounds__(256)
void k_gemm_bf(const unsigned short* __restrict__ A, const unsigned short* __restrict__ Bt,
               const float* __restrict__ bias, unsigned short* __restrict__ C,
               int M, int K, int N, int do_relu) {
    __shared__ __align__(16) char Asl[128 * 64];
    __shared__ __align__(16) char Bsl[128 * 64];
    const int t = threadIdx.x;
    const int m0 = blockIdx.y * 128, n0 = blockIdx.x * 128;
    const int wid = t >> 6, l = t & 63;
    const int wr = (wid >> 1) * 64, wc = (wid & 1) * 64;
    const int lrow = l & 15, g = l >> 4;

    const int srow = (l >> 2);
    const int cb_src = ((l & 3) * 16) ^ ((srow & 3) << 4);
    const int r0 = wid * 32 + srow, r1 = r0 + 16;
    const size_t rowA0 = (size_t)min(m0 + r0, M - 1) * K * 2;
    const size_t rowA1 = (size_t)min(m0 + r1, M - 1) * K * 2;
    const size_t rowB0 = (size_t)(n0 + r0) * K * 2;
    const size_t rowB1 = (size_t)(n0 + r1) * K * 2;
    const char* Ab = (const char*)A;
    const char* Bb = (const char*)Bt;
    char* ldsA0 = Asl + (wid * 32) * 64;
    char* ldsA1 = ldsA0 + 16 * 64;
    char* ldsB0 = Bsl + (wid * 32) * 64;
    char* ldsB1 = ldsB0 + 16 * 64;

    f32x4 acc[4][4] = {};
    for (int k0 = 0; k0 < K; k0 += 32) {
        const size_t koff = (size_t)k0 * 2 + cb_src;
        gload16(Ab + rowA0 + koff, ldsA0);
        gload16(Ab + rowA1 + koff, ldsA1);
        gload16(Bb + rowB0 + koff, ldsB0);
        gload16(Bb + rowB1 + koff, ldsB1);
        __syncthreads();
        bf16x8 af[4], bfr[4];
#pragma unroll
        for (int i = 0; i < 4; ++i)
            af[i] = *(const bf16x8*)(Asl + (wr + i * 16 + lrow) * 64 + ((g * 16) ^ ((lrow & 3) << 4)));
#pragma unroll
        for (int j = 0; j < 4; ++j)
            bfr[j] = *(const bf16x8*)(Bsl + (wc + j * 16 + lrow) * 64 + ((g * 16) ^ ((lrow & 3) << 4)));
#pragma unroll
        for (int i = 0; i < 4; ++i)
#pragma unroll
            for (int j = 0; j < 4; ++j)
                acc[i][j] = __builtin_amdgcn_mfma_f32_16x16x32_bf16(af[i], bfr[j], acc[i][j], 0, 0, 0);
        __syncthreads();
    }
    float bv[4];
#pragma unroll
    for (int j = 0; j < 4; ++j) bv[j] = bias[n0 + wc + j * 16 + lrow];
#pragma unroll
    for (int i = 0; i < 4; ++i) {
        const int rb = m0 + wr + i * 16 + g * 4;
#pragma unroll
        for (int e = 0; e < 4; ++e) {
            const int row = rb + e;
            if (row < M) {
#pragma unroll
                for (int j = 0; j < 4; ++j) {
                    float vv = acc[i][j][e] + bv[j];
                    if (do_relu) vv = fmaxf(vv, 0.f);
                    C[(size_t)row * N + n0 + wc + j * 16 + lrow] = (unsigned short)cvt_bf(vv);
                }
            }
        }
    }
}

// ---------------- pair pass: out = sigmoid( relu(u'[p0]+v[p1]) . w2 + lpb2 ) ----------------
// one wave per pair; uv[node] = [u'(512) | v(512)] bf16.

__global__ __launch_bounds__(256)
void k_pair(const unsigned short* __restrict__ uv, const int* __restrict__ pair, int P,
            const float* __restrict__ w2, const float* __restrict__ lpb2,
            float* __restrict__ out) {
    const int idx = (blockIdx.x * TPB + threadIdx.x) >> 6;
    if (idx >= P) return;
    const int lane = threadIdx.x & 63;
    const int p0n = pair[idx], p1n = pair[P + idx];
    const uint4 a = *(const uint4*)(uv + (size_t)p0n * 1024 + lane * 8);
    const uint4 b = *(const uint4*)(uv + (size_t)p1n * 1024 + 512 + lane * 8);
    const float4 w0 = *(const float4*)(w2 + lane * 8);
    const float4 w1 = *(const float4*)(w2 + lane * 8 + 4);
    const unsigned ua[4] = {a.x, a.y, a.z, a.w};
    const unsigned ub[4] = {b.x, b.y, b.z, b.w};
    const float wv[8] = {w0.x, w0.y, w0.z, w0.w, w1.x, w1.y, w1.z, w1.w};
    float s = 0.f;
#pragma unroll
    for (int q = 0; q < 4; ++q) {
        float h0 = __uint_as_float(ua[q] << 16) + __uint_as_float(ub[q] << 16);
        float h1 = __uint_as_float(ua[q] & 0xffff0000u) + __uint_as_float(ub[q] & 0xffff0000u);
        s = fmaf(fmaxf(h0, 0.f), wv[2 * q], s);
        s = fmaf(fmaxf(h1, 0.f), wv[2 * q + 1], s);
    }
    s += __shfl_xor(s, 1, 64);
    s += __shfl_xor(s, 2, 64);
    s += __shfl_xor(s, 4, 64);
    s += __shfl_xor(s, 8, 64);
    s += __shfl_xor(s, 16, 64);
    s += __shfl_xor(s, 32, 64);
    if (lane == 0) out[idx] = 1.0f / (1.0f + expf(-(s + lpb2[0])));
}

// ---------------- launcher ----------------

extern "C" void kernel_launch(void* const* d_in, const int* in_sizes, int n_in,
                              void* d_out, int out_size, void* d_ws, size_t ws_size,
                              hipStream_t stream) {
    const float* x    = (const float*)d_in[0];
    const int*   ei   = (const int*)d_in[1];
    const int*   ep   = (const int*)d_in[2];
    const float* W1   = (const float*)d_in[3];
    const float* b1   = (const float*)d_in[4];
    const float* W2   = (const float*)d_in[5];
    const float* b2   = (const float*)d_in[6];
    const float* lpW1 = (const float*)d_in[7];
    const float* lpb1 = (const float*)d_in[8];
    const float* lpW2 = (const float*)d_in[9];
    const float* lpb2 = (const float*)d_in[10];

    const int n = in_sizes[0] / 512;
    const int E = in_sizes[1] / 2;
    const int P = in_sizes[2] / 2;
    const int* src = ei;
    const int* dst = ei + E;

    char* w = (char*)d_ws;
    size_t off = 0;
    auto alloc = [&](size_t bytes) {
        void* p = w + off;
        off = (off + bytes + 255) & ~(size_t)255;
        return p;
    };
    int*   cnt       = (int*)alloc((size_t)n * 4);
    int*   row_start = (int*)alloc((size_t)(n + 1) * 4);
    int*   cursor    = (int*)alloc((size_t)n * 4);
    int*   csr_src   = (int*)alloc((size_t)E * 4);
    float* csr_nrm   = (float*)alloc((size_t)E * 4);
    float* dis       = (float*)alloc((size_t)n * 4);
    unsigned short* w1t    = (unsigned short*)alloc((size_t)512 * 512 * 2);
    unsigned short* w2bf   = (unsigned short*)alloc((size_t)512 * 512 * 2);
    unsigned short* lpw1t  = (unsigned short*)alloc((size_t)1024 * 512 * 2);
    unsigned short* wfT    = (unsigned short*)alloc((size_t)1024 * 512 * 2);
    float* bias_big  = (float*)alloc((size_t)1024 * 4);
    float* zerob     = (float*)alloc((size_t)1024 * 4);
    unsigned short* bufA = (unsigned short*)alloc((size_t)n * 512 * 2);
    unsigned short* bufB = (unsigned short*)alloc((size_t)n * 512 * 2);
    unsigned short* uv   = (unsigned short*)alloc((size_t)n * 1024 * 2);

    dim3 blk(TPB);
    const int nb_n = (n + TPB - 1) / TPB;
    const int nb_E = (E + TPB - 1) / TPB;

    // CSR build + norms
    k_zero_int<<<nb_n, blk, 0, stream>>>(cnt, n);
    k_hist<<<nb_E, blk, 0, stream>>>(dst, cnt, E);
    k_scan<<<1, 1024, 0, stream>>>(cnt, row_start, cursor, n);
    k_dis<<<nb_n, blk, 0, stream>>>(cnt, dis, n);
    k_fill_csr<<<nb_E, blk, 0, stream>>>(src, dst, dis, cursor, csr_src, csr_nrm, E);

    // conversions + weight fusion prep
    k_f2bf<<<(n * 64 + TPB - 1) / TPB, blk, 0, stream>>>(x, bufA, n * 64);
    k_cvtT<<<(512 * 512 + TPB - 1) / TPB, blk, 0, stream>>>(W1, w1t, 512, 512);
    k_f2bf<<<(512 * 64 + TPB - 1) / TPB, blk, 0, stream>>>(W2, w2bf, 512 * 64);
    k_cvtT_lp<<<(1024 * 512 + TPB - 1) / TPB, blk, 0, stream>>>(lpW1, lpw1t);
    k_fill0<<<(1024 + TPB - 1) / TPB, blk, 0, stream>>>(zerob, 1024);
    k_bias_lp<<<(1024 + TPB - 1) / TPB, blk, 0, stream>>>(lpW1, b2, lpb1, bias_big);
    // WfusedT[j][i] = sum_k lpW1ext[k][j] * W2[i][k]  -> [1024,512] bf16 Bt layout
    k_gemm_bf<<<dim3(4, 8), blk, 0, stream>>>(lpw1t, w2bf, zerob, wfT, 1024, 512, 512, 0);

    const int gy = (n + 127) / 128;
    const int agg_blocks = (n * 64 + TPB - 1) / TPB;

    // layer 1: y1 = A_hat x ; z1 = relu(y1 @ W1 + b1)
    k_agg_bf<<<agg_blocks, blk, 0, stream>>>(bufA, row_start, csr_src, csr_nrm, dis, bufB, n);
    k_gemm_bf<<<dim3(4, gy), blk, 0, stream>>>(bufB, w1t, b1, bufA, n, 512, 512, 1);
    // layer 2 folded into LP node-GEMM: y2 = A_hat z1 ; uv = y2 @ Wfused + bias_big
    k_agg_bf<<<agg_blocks, blk, 0, stream>>>(bufA, row_start, csr_src, csr_nrm, dis, bufB, n);
    k_gemm_bf<<<dim3(8, gy), blk, 0, stream>>>(bufB, wfT, bias_big, uv, n, 512, 1024, 0);

    // pair pass (fused relu + dot + sigmoid)
    k_pair<<<(P * 64 + TPB - 1) / TPB, blk, 0, stream>>>(uv, ep, P, lpW2, lpb2, (float*)d_out);
}

// Round 7
// 463.059 us; speedup vs baseline: 18.7155x; 1.2426x over previous
//
#include <hip/hip_runtime.h>
#include <math.h>

#define TPB 256

typedef __attribute__((ext_vector_type(8))) short bf16x8;
typedef __attribute__((ext_vector_type(4))) float f32x4;

__device__ __forceinline__ unsigned cvt_bf(float f) {
    unsigned u = __float_as_uint(f);
    u += 0x7fffu + ((u >> 16) & 1u);   // round-to-nearest-even
    return u >> 16;
}
__device__ __forceinline__ unsigned pack2(float a, float b) {
    return cvt_bf(a) | (cvt_bf(b) << 16);
}

// async global->LDS, 16B per lane; LDS dest = wave-uniform base + lane*16
__device__ __forceinline__ void gload16(const void* g, void* l) {
    __builtin_amdgcn_global_load_lds(
        (const __attribute__((address_space(1))) void*)g,
        (__attribute__((address_space(3))) void*)l, 16, 0, 0);
}

// ---------------- degree / CSR build ----------------

__global__ void k_hist(const int* __restrict__ dst, int* __restrict__ cnt, int E) {
    int e = blockIdx.x * TPB + threadIdx.x;
    if (e < E) atomicAdd(&cnt[dst[e]], 1);
}

// phase 1: per-block (256-wide) inclusive scan; emit block sums
__global__ __launch_bounds__(256)
void k_scan1(const int* __restrict__ cnt, int* __restrict__ incl,
             int* __restrict__ bsum, int n) {
    __shared__ int sh[256];
    const int t = threadIdx.x;
    const int i = blockIdx.x * 256 + t;
    int v = (i < n) ? cnt[i] : 0;
    sh[t] = v;
    __syncthreads();
#pragma unroll
    for (int d = 1; d < 256; d <<= 1) {
        int u = (t >= d) ? sh[t - d] : 0;
        __syncthreads();
        sh[t] += u;
        __syncthreads();
    }
    if (i < n) incl[i] = sh[t];
    if (t == 255) bsum[blockIdx.x] = sh[255];
}

// phase 2: single small block scans block sums (nb <= 256)
__global__ __launch_bounds__(256)
void k_scan2(int* __restrict__ bsum, int* __restrict__ boff,
             int* __restrict__ row_start, int n, int nb) {
    __shared__ int sh[256];
    const int t = threadIdx.x;
    int v = (t < nb) ? bsum[t] : 0;
    sh[t] = v;
    __syncthreads();
#pragma unroll
    for (int d = 1; d < 256; d <<= 1) {
        int u = (t >= d) ? sh[t - d] : 0;
        __syncthreads();
        sh[t] += u;
        __syncthreads();
    }
    if (t < nb) boff[t] = sh[t] - v;          // exclusive block offset
    if (t == nb - 1) row_start[n] = sh[t];    // grand total
}

// phase 3: row_start/cursor = exclusive scan; dis = rsqrt(deg+1)
__global__ void k_scan3(const int* __restrict__ cnt, const int* __restrict__ incl,
                        const int* __restrict__ boff, int* __restrict__ row_start,
                        int* __restrict__ cursor, float* __restrict__ dis, int n) {
    int i = blockIdx.x * TPB + threadIdx.x;
    if (i >= n) return;
    int c = cnt[i];
    int ex = boff[i >> 8] + incl[i] - c;
    row_start[i] = ex;
    cursor[i] = ex;
    dis[i] = rsqrtf((float)c + 1.0f);
}

__global__ void k_fill_csr(const int* __restrict__ src, const int* __restrict__ dst,
                           const float* __restrict__ dis, int* __restrict__ cursor,
                           int* __restrict__ csr_src, float* __restrict__ csr_nrm, int E) {
    int e = blockIdx.x * TPB + threadIdx.x;
    if (e >= E) return;
    int s = src[e], d = dst[e];
    int pos = atomicAdd(&cursor[d], 1);
    csr_src[pos] = s;
    csr_nrm[pos] = dis[s] * dis[d];
}

// ---------------- conversions ----------------

__global__ void k_f2bf(const float* __restrict__ in, unsigned short* __restrict__ out, int total8) {
    int i = blockIdx.x * TPB + threadIdx.x;
    if (i >= total8) return;
    float4 f0 = *(const float4*)(in + (size_t)i * 8);
    float4 f1 = *(const float4*)(in + (size_t)i * 8 + 4);
    uint4 o;
    o.x = pack2(f0.x, f0.y); o.y = pack2(f0.z, f0.w);
    o.z = pack2(f1.x, f1.y); o.w = pack2(f1.z, f1.w);
    *(uint4*)(out + (size_t)i * 8) = o;
}

// out[n][k] = bf16(in[k][n])   (in: [K,N] row-major)
__global__ void k_cvtT(const float* __restrict__ in, unsigned short* __restrict__ out, int K, int N) {
    int id = blockIdx.x * TPB + threadIdx.x;
    if (id >= K * N) return;
    int k = id / N, nn = id % N;
    out[(size_t)nn * K + k] = (unsigned short)cvt_bf(in[id]);
}

// lpW1 [1024,512] -> out [1024,512] Bt-ext layout:
// out[j][k] = (j<512) ? lpW1[k][j] : lpW1[512+k][j-512]
__global__ void k_cvtT_lp(const float* __restrict__ in, unsigned short* __restrict__ out) {
    int id = blockIdx.x * TPB + threadIdx.x;
    if (id >= 1024 * 512) return;
    int j = id >> 9, k = id & 511;
    float v = (j < 512) ? in[(size_t)k * 512 + j] : in[(size_t)(512 + k) * 512 + (j - 512)];
    out[id] = (unsigned short)cvt_bf(v);
}

// bias_big[j] = (j<512 ? lpb1[j] : 0) + sum_k b2[k]*lpW1ext[k][j]
// one wave per output column j, shuffle-reduced.
__global__ __launch_bounds__(256)
void k_bias_lp(const float* __restrict__ lpW1, const float* __restrict__ b2,
               const float* __restrict__ lpb1, float* __restrict__ bias_big) {
    const int j = blockIdx.x * 4 + (threadIdx.x >> 6);
    if (j >= 1024) return;
    const int lane = threadIdx.x & 63;
    const int col = (j < 512) ? j : (j - 512);
    const int ro = (j < 512) ? 0 : 512;
    float s = 0.f;
#pragma unroll
    for (int it = 0; it < 8; ++it) {
        int k = lane + it * 64;
        s = fmaf(b2[k], lpW1[(size_t)(ro + k) * 512 + col], s);
    }
    s += __shfl_xor(s, 1, 64);
    s += __shfl_xor(s, 2, 64);
    s += __shfl_xor(s, 4, 64);
    s += __shfl_xor(s, 8, 64);
    s += __shfl_xor(s, 16, 64);
    s += __shfl_xor(s, 32, 64);
    if (lane == 0) bias_big[j] = s + ((j < 512) ? lpb1[j] : 0.f);
}

// ---------------- CSR gather aggregation (bf16 in, bf16 out) ----------------

__global__ __launch_bounds__(256)
void k_agg_bf(const unsigned short* __restrict__ xin, const int* __restrict__ row_start,
              const int* __restrict__ csr_src, const float* __restrict__ csr_nrm,
              const float* __restrict__ dis, unsigned short* __restrict__ out, int n) {
    const int v = (blockIdx.x * TPB + threadIdx.x) >> 6;
    if (v >= n) return;
    const int lane = threadIdx.x & 63;
    const uint4* base = (const uint4*)xin;

    float d = dis[v]; float d2 = d * d;
    float acc[8];
    {
        uint4 u = base[(size_t)v * 64 + lane];
        acc[0] = d2 * __uint_as_float(u.x << 16);
        acc[1] = d2 * __uint_as_float(u.x & 0xffff0000u);
        acc[2] = d2 * __uint_as_float(u.y << 16);
        acc[3] = d2 * __uint_as_float(u.y & 0xffff0000u);
        acc[4] = d2 * __uint_as_float(u.z << 16);
        acc[5] = d2 * __uint_as_float(u.z & 0xffff0000u);
        acc[6] = d2 * __uint_as_float(u.w << 16);
        acc[7] = d2 * __uint_as_float(u.w & 0xffff0000u);
    }
    const int beg = row_start[v], end = row_start[v + 1];
    for (int j = beg; j < end; ++j) {
        int s = csr_src[j];
        float r = csr_nrm[j];
        uint4 u = base[(size_t)s * 64 + lane];
        acc[0] = fmaf(__uint_as_float(u.x << 16), r, acc[0]);
        acc[1] = fmaf(__uint_as_float(u.x & 0xffff0000u), r, acc[1]);
        acc[2] = fmaf(__uint_as_float(u.y << 16), r, acc[2]);
        acc[3] = fmaf(__uint_as_float(u.y & 0xffff0000u), r, acc[3]);
        acc[4] = fmaf(__uint_as_float(u.z << 16), r, acc[4]);
        acc[5] = fmaf(__uint_as_float(u.z & 0xffff0000u), r, acc[5]);
        acc[6] = fmaf(__uint_as_float(u.w << 16), r, acc[6]);
        acc[7] = fmaf(__uint_as_float(u.w & 0xffff0000u), r, acc[7]);
    }
    uint4 o;
    o.x = pack2(acc[0], acc[1]); o.y = pack2(acc[2], acc[3]);
    o.z = pack2(acc[4], acc[5]); o.w = pack2(acc[6], acc[7]);
    ((uint4*)out)[(size_t)v * 64 + lane] = o;
}

// ---------------- bf16 MFMA GEMM with fused bias(+relu), bf16 out ----------------
// C[M,N] = bf16( act( A[M,K] @ Bt[N,K]^T + bias ) )
// 128x128 tile, BK=32, 4 waves, pre-swizzled global_load_lds staging.

__global__ __launch_bounds__(256)
void k_gemm_bf(const unsigned short* __restrict__ A, const unsigned short* __restrict__ Bt,
               const float* __restrict__ bias, unsigned short* __restrict__ C,
               int M, int K, int N, int do_relu) {
    __shared__ __align__(16) char Asl[128 * 64];
    __shared__ __align__(16) char Bsl[128 * 64];
    const int t = threadIdx.x;
    const int m0 = blockIdx.y * 128, n0 = blockIdx.x * 128;
    const int wid = t >> 6, l = t & 63;
    const int wr = (wid >> 1) * 64, wc = (wid & 1) * 64;
    const int lrow = l & 15, g = l >> 4;

    const int srow = (l >> 2);
    const int cb_src = ((l & 3) * 16) ^ ((srow & 3) << 4);
    const int r0 = wid * 32 + srow, r1 = r0 + 16;
    const size_t rowA0 = (size_t)min(m0 + r0, M - 1) * K * 2;
    const size_t rowA1 = (size_t)min(m0 + r1, M - 1) * K * 2;
    const size_t rowB0 = (size_t)(n0 + r0) * K * 2;
    const size_t rowB1 = (size_t)(n0 + r1) * K * 2;
    const char* Ab = (const char*)A;
    const char* Bb = (const char*)Bt;
    char* ldsA0 = Asl + (wid * 32) * 64;
    char* ldsA1 = ldsA0 + 16 * 64;
    char* ldsB0 = Bsl + (wid * 32) * 64;
    char* ldsB1 = ldsB0 + 16 * 64;

    f32x4 acc[4][4] = {};
    for (int k0 = 0; k0 < K; k0 += 32) {
        const size_t koff = (size_t)k0 * 2 + cb_src;
        gload16(Ab + rowA0 + koff, ldsA0);
        gload16(Ab + rowA1 + koff, ldsA1);
        gload16(Bb + rowB0 + koff, ldsB0);
        gload16(Bb + rowB1 + koff, ldsB1);
        __syncthreads();
        bf16x8 af[4], bfr[4];
#pragma unroll
        for (int i = 0; i < 4; ++i)
            af[i] = *(const bf16x8*)(Asl + (wr + i * 16 + lrow) * 64 + ((g * 16) ^ ((lrow & 3) << 4)));
#pragma unroll
        for (int j = 0; j < 4; ++j)
            bfr[j] = *(const bf16x8*)(Bsl + (wc + j * 16 + lrow) * 64 + ((g * 16) ^ ((lrow & 3) << 4)));
#pragma unroll
        for (int i = 0; i < 4; ++i)
#pragma unroll
            for (int j = 0; j < 4; ++j)
                acc[i][j] = __builtin_amdgcn_mfma_f32_16x16x32_bf16(af[i], bfr[j], acc[i][j], 0, 0, 0);
        __syncthreads();
    }
    float bv[4];
#pragma unroll
    for (int j = 0; j < 4; ++j) bv[j] = bias[n0 + wc + j * 16 + lrow];
#pragma unroll
    for (int i = 0; i < 4; ++i) {
        const int rb = m0 + wr + i * 16 + g * 4;
#pragma unroll
        for (int e = 0; e < 4; ++e) {
            const int row = rb + e;
            if (row < M) {
#pragma unroll
                for (int j = 0; j < 4; ++j) {
                    float vv = acc[i][j][e] + bv[j];
                    if (do_relu) vv = fmaxf(vv, 0.f);
                    C[(size_t)row * N + n0 + wc + j * 16 + lrow] = (unsigned short)cvt_bf(vv);
                }
            }
        }
    }
}

// ---------------- pair pass: out = sigmoid( relu(u'[p0]+v[p1]) . w2 + lpb2 ) ----------------

__global__ __launch_bounds__(256)
void k_pair(const unsigned short* __restrict__ uv, const int* __restrict__ pair, int P,
            const float* __restrict__ w2, const float* __restrict__ lpb2,
            float* __restrict__ out) {
    const int idx = (blockIdx.x * TPB + threadIdx.x) >> 6;
    if (idx >= P) return;
    const int lane = threadIdx.x & 63;
    const int p0n = pair[idx], p1n = pair[P + idx];
    const uint4 a = *(const uint4*)(uv + (size_t)p0n * 1024 + lane * 8);
    const uint4 b = *(const uint4*)(uv + (size_t)p1n * 1024 + 512 + lane * 8);
    const float4 w0 = *(const float4*)(w2 + lane * 8);
    const float4 w1 = *(const float4*)(w2 + lane * 8 + 4);
    const unsigned ua[4] = {a.x, a.y, a.z, a.w};
    const unsigned ub[4] = {b.x, b.y, b.z, b.w};
    const float wv[8] = {w0.x, w0.y, w0.z, w0.w, w1.x, w1.y, w1.z, w1.w};
    float s = 0.f;
#pragma unroll
    for (int q = 0; q < 4; ++q) {
        float h0 = __uint_as_float(ua[q] << 16) + __uint_as_float(ub[q] << 16);
        float h1 = __uint_as_float(ua[q] & 0xffff0000u) + __uint_as_float(ub[q] & 0xffff0000u);
        s = fmaf(fmaxf(h0, 0.f), wv[2 * q], s);
        s = fmaf(fmaxf(h1, 0.f), wv[2 * q + 1], s);
    }
    s += __shfl_xor(s, 1, 64);
    s += __shfl_xor(s, 2, 64);
    s += __shfl_xor(s, 4, 64);
    s += __shfl_xor(s, 8, 64);
    s += __shfl_xor(s, 16, 64);
    s += __shfl_xor(s, 32, 64);
    if (lane == 0) out[idx] = 1.0f / (1.0f + expf(-(s + lpb2[0])));
}

// ---------------- launcher ----------------

extern "C" void kernel_launch(void* const* d_in, const int* in_sizes, int n_in,
                              void* d_out, int out_size, void* d_ws, size_t ws_size,
                              hipStream_t stream) {
    const float* x    = (const float*)d_in[0];
    const int*   ei   = (const int*)d_in[1];
    const int*   ep   = (const int*)d_in[2];
    const float* W1   = (const float*)d_in[3];
    const float* b1   = (const float*)d_in[4];
    const float* W2   = (const float*)d_in[5];
    const float* b2   = (const float*)d_in[6];
    const float* lpW1 = (const float*)d_in[7];
    const float* lpb1 = (const float*)d_in[8];
    const float* lpW2 = (const float*)d_in[9];
    const float* lpb2 = (const float*)d_in[10];

    const int n = in_sizes[0] / 512;
    const int E = in_sizes[1] / 2;
    const int P = in_sizes[2] / 2;
    const int* src = ei;
    const int* dst = ei + E;

    char* w = (char*)d_ws;
    size_t off = 0;
    auto alloc = [&](size_t bytes) {
        void* p = w + off;
        off = (off + bytes + 255) & ~(size_t)255;
        return p;
    };
    int*   cnt       = (int*)alloc((size_t)n * 4);
    int*   incl      = (int*)alloc((size_t)n * 4);
    int*   bsum      = (int*)alloc((size_t)256 * 4);
    int*   boff      = (int*)alloc((size_t)256 * 4);
    int*   row_start = (int*)alloc((size_t)(n + 1) * 4);
    int*   cursor    = (int*)alloc((size_t)n * 4);
    int*   csr_src   = (int*)alloc((size_t)E * 4);
    float* csr_nrm   = (float*)alloc((size_t)E * 4);
    float* dis       = (float*)alloc((size_t)n * 4);
    unsigned short* w1t    = (unsigned short*)alloc((size_t)512 * 512 * 2);
    unsigned short* w2bf   = (unsigned short*)alloc((size_t)512 * 512 * 2);
    unsigned short* lpw1t  = (unsigned short*)alloc((size_t)1024 * 512 * 2);
    unsigned short* wfT    = (unsigned short*)alloc((size_t)1024 * 512 * 2);
    float* bias_big  = (float*)alloc((size_t)1024 * 4);
    float* zerob     = (float*)alloc((size_t)1024 * 4);
    unsigned short* bufA = (unsigned short*)alloc((size_t)n * 512 * 2);
    unsigned short* bufB = (unsigned short*)alloc((size_t)n * 512 * 2);
    unsigned short* uv   = (unsigned short*)alloc((size_t)n * 1024 * 2);

    dim3 blk(TPB);
    const int nb_n = (n + TPB - 1) / TPB;
    const int nb_E = (E + TPB - 1) / TPB;
    const int nb_scan = (n + 255) / 256;

    // CSR build + norms
    hipMemsetAsync(cnt, 0, (size_t)n * 4, stream);
    hipMemsetAsync(zerob, 0, (size_t)1024 * 4, stream);
    k_hist<<<nb_E, blk, 0, stream>>>(dst, cnt, E);
    k_scan1<<<nb_scan, 256, 0, stream>>>(cnt, incl, bsum, n);
    k_scan2<<<1, 256, 0, stream>>>(bsum, boff, row_start, n, nb_scan);
    k_scan3<<<nb_n, blk, 0, stream>>>(cnt, incl, boff, row_start, cursor, dis, n);
    k_fill_csr<<<nb_E, blk, 0, stream>>>(src, dst, dis, cursor, csr_src, csr_nrm, E);

    // conversions + weight fusion prep
    k_f2bf<<<(n * 64 + TPB - 1) / TPB, blk, 0, stream>>>(x, bufA, n * 64);
    k_cvtT<<<(512 * 512 + TPB - 1) / TPB, blk, 0, stream>>>(W1, w1t, 512, 512);
    k_f2bf<<<(512 * 64 + TPB - 1) / TPB, blk, 0, stream>>>(W2, w2bf, 512 * 64);
    k_cvtT_lp<<<(1024 * 512 + TPB - 1) / TPB, blk, 0, stream>>>(lpW1, lpw1t);
    k_bias_lp<<<256, blk, 0, stream>>>(lpW1, b2, lpb1, bias_big);
    // WfusedT[j][i] = sum_k lpW1ext[k][j] * W2[i][k]  -> [1024,512] bf16 Bt layout
    k_gemm_bf<<<dim3(4, 8), blk, 0, stream>>>(lpw1t, w2bf, zerob, wfT, 1024, 512, 512, 0);

    const int gy = (n + 127) / 128;
    const int agg_blocks = (n * 64 + TPB - 1) / TPB;

    // layer 1: y1 = A_hat x ; z1 = relu(y1 @ W1 + b1)
    k_agg_bf<<<agg_blocks, blk, 0, stream>>>(bufA, row_start, csr_src, csr_nrm, dis, bufB, n);
    k_gemm_bf<<<dim3(4, gy), blk, 0, stream>>>(bufB, w1t, b1, bufA, n, 512, 512, 1);
    // layer 2 folded into LP node-GEMM: y2 = A_hat z1 ; uv = y2 @ Wfused + bias_big
    k_agg_bf<<<agg_blocks, blk, 0, stream>>>(bufA, row_start, csr_src, csr_nrm, dis, bufB, n);
    k_gemm_bf<<<dim3(8, gy), blk, 0, stream>>>(bufB, wfT, bias_big, uv, n, 512, 1024, 0);

    // pair pass (fused relu + dot + sigmoid)
    k_pair<<<(P * 64 + TPB - 1) / TPB, blk, 0, stream>>>(uv, ep, P, lpW2, lpb2, (float*)d_out);
}

// Round 8
// 447.890 us; speedup vs baseline: 19.3493x; 1.0339x over previous
//
#include <hip/hip_runtime.h>
#include <math.h>

#define TPB 256

typedef __attribute__((ext_vector_type(8))) short bf16x8;
typedef __attribute__((ext_vector_type(4))) float f32x4;

__device__ __forceinline__ unsigned cvt_bf(float f) {
    unsigned u = __float_as_uint(f);
    u += 0x7fffu + ((u >> 16) & 1u);   // round-to-nearest-even
    return u >> 16;
}
__device__ __forceinline__ unsigned pack2(float a, float b) {
    return cvt_bf(a) | (cvt_bf(b) << 16);
}

// async global->LDS, 16B per lane; LDS dest = wave-uniform base + lane*16
__device__ __forceinline__ void gload16(const void* g, void* l) {
    __builtin_amdgcn_global_load_lds(
        (const __attribute__((address_space(1))) void*)g,
        (__attribute__((address_space(3))) void*)l, 16, 0, 0);
}

// ---------------- degree / CSR build ----------------

__global__ void k_hist(const int* __restrict__ dst, int* __restrict__ cnt, int E) {
    int e = blockIdx.x * TPB + threadIdx.x;
    if (e < E) atomicAdd(&cnt[dst[e]], 1);
}

// phase 1: per-block (256-wide) inclusive scan; emit block sums
__global__ __launch_bounds__(256)
void k_scan1(const int* __restrict__ cnt, int* __restrict__ incl,
             int* __restrict__ bsum, int n) {
    __shared__ int sh[256];
    const int t = threadIdx.x;
    const int i = blockIdx.x * 256 + t;
    int v = (i < n) ? cnt[i] : 0;
    sh[t] = v;
    __syncthreads();
#pragma unroll
    for (int d = 1; d < 256; d <<= 1) {
        int u = (t >= d) ? sh[t - d] : 0;
        __syncthreads();
        sh[t] += u;
        __syncthreads();
    }
    if (i < n) incl[i] = sh[t];
    if (t == 255) bsum[blockIdx.x] = sh[255];
}

// phase 2: single small block scans block sums (nb <= 256)
__global__ __launch_bounds__(256)
void k_scan2(int* __restrict__ bsum, int* __restrict__ boff,
             int* __restrict__ row_start, int n, int nb) {
    __shared__ int sh[256];
    const int t = threadIdx.x;
    int v = (t < nb) ? bsum[t] : 0;
    sh[t] = v;
    __syncthreads();
#pragma unroll
    for (int d = 1; d < 256; d <<= 1) {
        int u = (t >= d) ? sh[t - d] : 0;
        __syncthreads();
        sh[t] += u;
        __syncthreads();
    }
    if (t < nb) boff[t] = sh[t] - v;          // exclusive block offset
    if (t == nb - 1) row_start[n] = sh[t];    // grand total
}

// phase 3: row_start/cursor = exclusive scan; dis = rsqrt(deg+1)
__global__ void k_scan3(const int* __restrict__ cnt, const int* __restrict__ incl,
                        const int* __restrict__ boff, int* __restrict__ row_start,
                        int* __restrict__ cursor, float* __restrict__ dis, int n) {
    int i = blockIdx.x * TPB + threadIdx.x;
    if (i >= n) return;
    int c = cnt[i];
    int ex = boff[i >> 8] + incl[i] - c;
    row_start[i] = ex;
    cursor[i] = ex;
    dis[i] = rsqrtf((float)c + 1.0f);
}

__global__ void k_fill_csr(const int* __restrict__ src, const int* __restrict__ dst,
                           const float* __restrict__ dis, int* __restrict__ cursor,
                           int* __restrict__ csr_src, float* __restrict__ csr_nrm, int E) {
    int e = blockIdx.x * TPB + threadIdx.x;
    if (e >= E) return;
    int s = src[e], d = dst[e];
    int pos = atomicAdd(&cursor[d], 1);
    csr_src[pos] = s;
    csr_nrm[pos] = dis[s] * dis[d];
}

// ---------------- conversions ----------------

__global__ void k_f2bf(const float* __restrict__ in, unsigned short* __restrict__ out, int total8) {
    int i = blockIdx.x * TPB + threadIdx.x;
    if (i >= total8) return;
    float4 f0 = *(const float4*)(in + (size_t)i * 8);
    float4 f1 = *(const float4*)(in + (size_t)i * 8 + 4);
    uint4 o;
    o.x = pack2(f0.x, f0.y); o.y = pack2(f0.z, f0.w);
    o.z = pack2(f1.x, f1.y); o.w = pack2(f1.z, f1.w);
    *(uint4*)(out + (size_t)i * 8) = o;
}

// out[n][k] = bf16(in[k][n])   (in: [K,N] row-major)
__global__ void k_cvtT(const float* __restrict__ in, unsigned short* __restrict__ out, int K, int N) {
    int id = blockIdx.x * TPB + threadIdx.x;
    if (id >= K * N) return;
    int k = id / N, nn = id % N;
    out[(size_t)nn * K + k] = (unsigned short)cvt_bf(in[id]);
}

// lpW1 [1024,512] -> out [1024,512] Bt-ext layout:
// out[j][k] = (j<512) ? lpW1[k][j] : lpW1[512+k][j-512]
__global__ void k_cvtT_lp(const float* __restrict__ in, unsigned short* __restrict__ out) {
    int id = blockIdx.x * TPB + threadIdx.x;
    if (id >= 1024 * 512) return;
    int j = id >> 9, k = id & 511;
    float v = (j < 512) ? in[(size_t)k * 512 + j] : in[(size_t)(512 + k) * 512 + (j - 512)];
    out[id] = (unsigned short)cvt_bf(v);
}

// bias_big[j] = (j<512 ? lpb1[j] : 0) + sum_k b2[k]*lpW1ext[k][j]
// one wave per output column j, shuffle-reduced.
__global__ __launch_bounds__(256)
void k_bias_lp(const float* __restrict__ lpW1, const float* __restrict__ b2,
               const float* __restrict__ lpb1, float* __restrict__ bias_big) {
    const int j = blockIdx.x * 4 + (threadIdx.x >> 6);
    if (j >= 1024) return;
    const int lane = threadIdx.x & 63;
    const int col = (j < 512) ? j : (j - 512);
    const int ro = (j < 512) ? 0 : 512;
    float s = 0.f;
#pragma unroll
    for (int it = 0; it < 8; ++it) {
        int k = lane + it * 64;
        s = fmaf(b2[k], lpW1[(size_t)(ro + k) * 512 + col], s);
    }
    s += __shfl_xor(s, 1, 64);
    s += __shfl_xor(s, 2, 64);
    s += __shfl_xor(s, 4, 64);
    s += __shfl_xor(s, 8, 64);
    s += __shfl_xor(s, 16, 64);
    s += __shfl_xor(s, 32, 64);
    if (lane == 0) bias_big[j] = s + ((j < 512) ? lpb1[j] : 0.f);
}

// ---------------- CSR gather aggregation (bf16 in, bf16 out) ----------------

__global__ __launch_bounds__(256)
void k_agg_bf(const unsigned short* __restrict__ xin, const int* __restrict__ row_start,
              const int* __restrict__ csr_src, const float* __restrict__ csr_nrm,
              const float* __restrict__ dis, unsigned short* __restrict__ out, int n) {
    const int v = (blockIdx.x * TPB + threadIdx.x) >> 6;
    if (v >= n) return;
    const int lane = threadIdx.x & 63;
    const uint4* base = (const uint4*)xin;

    float d = dis[v]; float d2 = d * d;
    float acc[8];
    {
        uint4 u = base[(size_t)v * 64 + lane];
        acc[0] = d2 * __uint_as_float(u.x << 16);
        acc[1] = d2 * __uint_as_float(u.x & 0xffff0000u);
        acc[2] = d2 * __uint_as_float(u.y << 16);
        acc[3] = d2 * __uint_as_float(u.y & 0xffff0000u);
        acc[4] = d2 * __uint_as_float(u.z << 16);
        acc[5] = d2 * __uint_as_float(u.z & 0xffff0000u);
        acc[6] = d2 * __uint_as_float(u.w << 16);
        acc[7] = d2 * __uint_as_float(u.w & 0xffff0000u);
    }
    const int beg = row_start[v], end = row_start[v + 1];
    for (int j = beg; j < end; ++j) {
        int s = csr_src[j];
        float r = csr_nrm[j];
        uint4 u = base[(size_t)s * 64 + lane];
        acc[0] = fmaf(__uint_as_float(u.x << 16), r, acc[0]);
        acc[1] = fmaf(__uint_as_float(u.x & 0xffff0000u), r, acc[1]);
        acc[2] = fmaf(__uint_as_float(u.y << 16), r, acc[2]);
        acc[3] = fmaf(__uint_as_float(u.y & 0xffff0000u), r, acc[3]);
        acc[4] = fmaf(__uint_as_float(u.z << 16), r, acc[4]);
        acc[5] = fmaf(__uint_as_float(u.z & 0xffff0000u), r, acc[5]);
        acc[6] = fmaf(__uint_as_float(u.w << 16), r, acc[6]);
        acc[7] = fmaf(__uint_as_float(u.w & 0xffff0000u), r, acc[7]);
    }
    uint4 o;
    o.x = pack2(acc[0], acc[1]); o.y = pack2(acc[2], acc[3]);
    o.z = pack2(acc[4], acc[5]); o.w = pack2(acc[6], acc[7]);
    ((uint4*)out)[(size_t)v * 64 + lane] = o;
}

// ---------------- bf16 MFMA GEMM with fused bias(+relu), bf16 out ----------------
// C[M,N] = bf16( act( A[M,K] @ Bt[N,K]^T + bias ) )
// 128x128 tile, BK=32, 4 waves, pre-swizzled global_load_lds staging.
// 1-D grid + XCD-aware swizzle: XCD owns full row-strips (A panel L2-local).

__global__ __launch_bounds__(256)
void k_gemm_bf(const unsigned short* __restrict__ A, const unsigned short* __restrict__ Bt,
               const float* __restrict__ bias, unsigned short* __restrict__ C,
               int M, int K, int N, int do_relu, int nbx) {
    const int lin = blockIdx.x;
    const int xcd = lin & 7, seq = lin >> 3;
    const int rowt = xcd + 8 * (seq / nbx);
    const int colt = seq % nbx;
    const int m0 = rowt * 128;
    if (m0 >= M + 127) return;          // padded tail block: no work
    const int n0 = colt * 128;

    __shared__ __align__(16) char Asl[128 * 64];
    __shared__ __align__(16) char Bsl[128 * 64];
    const int t = threadIdx.x;
    const int wid = t >> 6, l = t & 63;
    const int wr = (wid >> 1) * 64, wc = (wid & 1) * 64;
    const int lrow = l & 15, g = l >> 4;

    const int srow = (l >> 2);
    const int cb_src = ((l & 3) * 16) ^ ((srow & 3) << 4);
    const int r0 = wid * 32 + srow, r1 = r0 + 16;
    const size_t rowA0 = (size_t)min(m0 + r0, M - 1) * K * 2;
    const size_t rowA1 = (size_t)min(m0 + r1, M - 1) * K * 2;
    const size_t rowB0 = (size_t)(n0 + r0) * K * 2;
    const size_t rowB1 = (size_t)(n0 + r1) * K * 2;
    const char* Ab = (const char*)A;
    const char* Bb = (const char*)Bt;
    char* ldsA0 = Asl + (wid * 32) * 64;
    char* ldsA1 = ldsA0 + 16 * 64;
    char* ldsB0 = Bsl + (wid * 32) * 64;
    char* ldsB1 = ldsB0 + 16 * 64;

    f32x4 acc[4][4] = {};
    for (int k0 = 0; k0 < K; k0 += 32) {
        const size_t koff = (size_t)k0 * 2 + cb_src;
        gload16(Ab + rowA0 + koff, ldsA0);
        gload16(Ab + rowA1 + koff, ldsA1);
        gload16(Bb + rowB0 + koff, ldsB0);
        gload16(Bb + rowB1 + koff, ldsB1);
        __syncthreads();
        bf16x8 af[4], bfr[4];
#pragma unroll
        for (int i = 0; i < 4; ++i)
            af[i] = *(const bf16x8*)(Asl + (wr + i * 16 + lrow) * 64 + ((g * 16) ^ ((lrow & 3) << 4)));
#pragma unroll
        for (int j = 0; j < 4; ++j)
            bfr[j] = *(const bf16x8*)(Bsl + (wc + j * 16 + lrow) * 64 + ((g * 16) ^ ((lrow & 3) << 4)));
#pragma unroll
        for (int i = 0; i < 4; ++i)
#pragma unroll
            for (int j = 0; j < 4; ++j)
                acc[i][j] = __builtin_amdgcn_mfma_f32_16x16x32_bf16(af[i], bfr[j], acc[i][j], 0, 0, 0);
        __syncthreads();
    }
    float bv[4];
#pragma unroll
    for (int j = 0; j < 4; ++j) bv[j] = bias[n0 + wc + j * 16 + lrow];
#pragma unroll
    for (int i = 0; i < 4; ++i) {
        const int rb = m0 + wr + i * 16 + g * 4;
#pragma unroll
        for (int e = 0; e < 4; ++e) {
            const int row = rb + e;
            if (row < M) {
#pragma unroll
                for (int j = 0; j < 4; ++j) {
                    float vv = acc[i][j][e] + bv[j];
                    if (do_relu) vv = fmaxf(vv, 0.f);
                    C[(size_t)row * N + n0 + wc + j * 16 + lrow] = (unsigned short)cvt_bf(vv);
                }
            }
        }
    }
}

// ---------------- pair pass: out = sigmoid( relu(u'[p0]+v[p1]) . w2 + lpb2 ) ----------------

__global__ __launch_bounds__(256)
void k_pair(const unsigned short* __restrict__ uv, const int* __restrict__ pair, int P,
            const float* __restrict__ w2, const float* __restrict__ lpb2,
            float* __restrict__ out) {
    const int idx = (blockIdx.x * TPB + threadIdx.x) >> 6;
    if (idx >= P) return;
    const int lane = threadIdx.x & 63;
    const int p0n = pair[idx], p1n = pair[P + idx];
    const uint4 a = *(const uint4*)(uv + (size_t)p0n * 1024 + lane * 8);
    const uint4 b = *(const uint4*)(uv + (size_t)p1n * 1024 + 512 + lane * 8);
    const float4 w0 = *(const float4*)(w2 + lane * 8);
    const float4 w1 = *(const float4*)(w2 + lane * 8 + 4);
    const unsigned ua[4] = {a.x, a.y, a.z, a.w};
    const unsigned ub[4] = {b.x, b.y, b.z, b.w};
    const float wv[8] = {w0.x, w0.y, w0.z, w0.w, w1.x, w1.y, w1.z, w1.w};
    float s = 0.f;
#pragma unroll
    for (int q = 0; q < 4; ++q) {
        float h0 = __uint_as_float(ua[q] << 16) + __uint_as_float(ub[q] << 16);
        float h1 = __uint_as_float(ua[q] & 0xffff0000u) + __uint_as_float(ub[q] & 0xffff0000u);
        s = fmaf(fmaxf(h0, 0.f), wv[2 * q], s);
        s = fmaf(fmaxf(h1, 0.f), wv[2 * q + 1], s);
    }
    s += __shfl_xor(s, 1, 64);
    s += __shfl_xor(s, 2, 64);
    s += __shfl_xor(s, 4, 64);
    s += __shfl_xor(s, 8, 64);
    s += __shfl_xor(s, 16, 64);
    s += __shfl_xor(s, 32, 64);
    if (lane == 0) out[idx] = 1.0f / (1.0f + expf(-(s + lpb2[0])));
}

// ---------------- launcher ----------------

extern "C" void kernel_launch(void* const* d_in, const int* in_sizes, int n_in,
                              void* d_out, int out_size, void* d_ws, size_t ws_size,
                              hipStream_t stream) {
    const float* x    = (const float*)d_in[0];
    const int*   ei   = (const int*)d_in[1];
    const int*   ep   = (const int*)d_in[2];
    const float* W1   = (const float*)d_in[3];
    const float* b1   = (const float*)d_in[4];
    const float* W2   = (const float*)d_in[5];
    const float* b2   = (const float*)d_in[6];
    const float* lpW1 = (const float*)d_in[7];
    const float* lpb1 = (const float*)d_in[8];
    const float* lpW2 = (const float*)d_in[9];
    const float* lpb2 = (const float*)d_in[10];

    const int n = in_sizes[0] / 512;
    const int E = in_sizes[1] / 2;
    const int P = in_sizes[2] / 2;
    const int* src = ei;
    const int* dst = ei + E;

    char* w = (char*)d_ws;
    size_t off = 0;
    auto alloc = [&](size_t bytes) {
        void* p = w + off;
        off = (off + bytes + 255) & ~(size_t)255;
        return p;
    };
    int*   cnt       = (int*)alloc((size_t)n * 4);
    int*   incl      = (int*)alloc((size_t)n * 4);
    int*   bsum      = (int*)alloc((size_t)256 * 4);
    int*   boff      = (int*)alloc((size_t)256 * 4);
    int*   row_start = (int*)alloc((size_t)(n + 1) * 4);
    int*   cursor    = (int*)alloc((size_t)n * 4);
    int*   csr_src   = (int*)alloc((size_t)E * 4);
    float* csr_nrm   = (float*)alloc((size_t)E * 4);
    float* dis       = (float*)alloc((size_t)n * 4);
    unsigned short* w1t    = (unsigned short*)alloc((size_t)512 * 512 * 2);
    unsigned short* w2bf   = (unsigned short*)alloc((size_t)512 * 512 * 2);
    unsigned short* lpw1t  = (unsigned short*)alloc((size_t)1024 * 512 * 2);
    unsigned short* wfT    = (unsigned short*)alloc((size_t)1024 * 512 * 2);
    float* bias_big  = (float*)alloc((size_t)1024 * 4);
    float* zerob     = (float*)alloc((size_t)1024 * 4);
    unsigned short* bufA = (unsigned short*)alloc((size_t)n * 512 * 2);
    unsigned short* bufB = (unsigned short*)alloc((size_t)n * 512 * 2);
    unsigned short* uv   = (unsigned short*)alloc((size_t)n * 1024 * 2);

    dim3 blk(TPB);
    const int nb_n = (n + TPB - 1) / TPB;
    const int nb_E = (E + TPB - 1) / TPB;
    const int nb_scan = (n + 255) / 256;

    // CSR build + norms
    hipMemsetAsync(cnt, 0, (size_t)n * 4, stream);
    hipMemsetAsync(zerob, 0, (size_t)1024 * 4, stream);
    k_hist<<<nb_E, blk, 0, stream>>>(dst, cnt, E);
    k_scan1<<<nb_scan, 256, 0, stream>>>(cnt, incl, bsum, n);
    k_scan2<<<1, 256, 0, stream>>>(bsum, boff, row_start, n, nb_scan);
    k_scan3<<<nb_n, blk, 0, stream>>>(cnt, incl, boff, row_start, cursor, dis, n);
    k_fill_csr<<<nb_E, blk, 0, stream>>>(src, dst, dis, cursor, csr_src, csr_nrm, E);

    // conversions + weight fusion prep
    k_f2bf<<<(n * 64 + TPB - 1) / TPB, blk, 0, stream>>>(x, bufA, n * 64);
    k_cvtT<<<(512 * 512 + TPB - 1) / TPB, blk, 0, stream>>>(W1, w1t, 512, 512);
    k_f2bf<<<(512 * 64 + TPB - 1) / TPB, blk, 0, stream>>>(W2, w2bf, 512 * 64);
    k_cvtT_lp<<<(1024 * 512 + TPB - 1) / TPB, blk, 0, stream>>>(lpW1, lpw1t);
    k_bias_lp<<<256, blk, 0, stream>>>(lpW1, b2, lpb1, bias_big);

    const int gy  = (n + 127) / 128;
    const int gy8 = ((gy + 7) / 8) * 8;
    const int agg_blocks = (n * 64 + TPB - 1) / TPB;

    // WfusedT[j][i] = sum_k lpW1ext[k][j] * W2[i][k]  -> [1024,512] bf16 Bt layout
    k_gemm_bf<<<4 * 8, blk, 0, stream>>>(lpw1t, w2bf, zerob, wfT, 1024, 512, 512, 0, 4);

    // layer 1: y1 = A_hat x ; z1 = relu(y1 @ W1 + b1)
    k_agg_bf<<<agg_blocks, blk, 0, stream>>>(bufA, row_start, csr_src, csr_nrm, dis, bufB, n);
    k_gemm_bf<<<4 * gy8, blk, 0, stream>>>(bufB, w1t, b1, bufA, n, 512, 512, 1, 4);
    // layer 2 folded into LP node-GEMM: y2 = A_hat z1 ; uv = y2 @ Wfused + bias_big
    k_agg_bf<<<agg_blocks, blk, 0, stream>>>(bufA, row_start, csr_src, csr_nrm, dis, bufB, n);
    k_gemm_bf<<<8 * gy8, blk, 0, stream>>>(bufB, wfT, bias_big, uv, n, 512, 1024, 0, 8);

    // pair pass (fused relu + dot + sigmoid)
    k_pair<<<(P * 64 + TPB - 1) / TPB, blk, 0, stream>>>(uv, ep, P, lpW2, lpb2, (float*)d_out);
}

// Round 10
// 442.253 us; speedup vs baseline: 19.5960x; 1.0127x over previous
//
#include <hip/hip_runtime.h>
#include <hip/hip_bf16.h>
#include <math.h>

#define TPB 256

typedef __attribute__((ext_vector_type(8))) short bf16x8;
typedef __attribute__((ext_vector_type(4))) float f32x4;

__device__ __forceinline__ unsigned cvt_bf(float f) {
    unsigned u = __float_as_uint(f);
    u += 0x7fffu + ((u >> 16) & 1u);   // round-to-nearest-even
    return u >> 16;
}
__device__ __forceinline__ unsigned pack2(float a, float b) {
    return cvt_bf(a) | (cvt_bf(b) << 16);
}
// packed f32->bf16x2 via compiler (v_cvt_pk_bf16_f32 on gfx950)
__device__ __forceinline__ unsigned pack2f(float a, float b) {
    __hip_bfloat162 h = __float22bfloat162_rn(float2{a, b});
    unsigned u;
    __builtin_memcpy(&u, &h, 4);
    return u;
}

// async global->LDS, 16B per lane; LDS dest = wave-uniform base + lane*16
__device__ __forceinline__ void gload16(const void* g, void* l) {
    __builtin_amdgcn_global_load_lds(
        (const __attribute__((address_space(1))) void*)g,
        (__attribute__((address_space(3))) void*)l, 16, 0, 0);
}

// ---------------- degree / CSR build ----------------

__global__ void k_hist(const int* __restrict__ dst, int* __restrict__ cnt, int E) {
    int e = blockIdx.x * TPB + threadIdx.x;
    if (e < E) atomicAdd(&cnt[dst[e]], 1);
}

__global__ __launch_bounds__(256)
void k_scan1(const int* __restrict__ cnt, int* __restrict__ incl,
             int* __restrict__ bsum, int n) {
    __shared__ int sh[256];
    const int t = threadIdx.x;
    const int i = blockIdx.x * 256 + t;
    int v = (i < n) ? cnt[i] : 0;
    sh[t] = v;
    __syncthreads();
#pragma unroll
    for (int d = 1; d < 256; d <<= 1) {
        int u = (t >= d) ? sh[t - d] : 0;
        __syncthreads();
        sh[t] += u;
        __syncthreads();
    }
    if (i < n) incl[i] = sh[t];
    if (t == 255) bsum[blockIdx.x] = sh[255];
}

__global__ __launch_bounds__(256)
void k_scan2(int* __restrict__ bsum, int* __restrict__ boff,
             int* __restrict__ row_start, int n, int nb) {
    __shared__ int sh[256];
    const int t = threadIdx.x;
    int v = (t < nb) ? bsum[t] : 0;
    sh[t] = v;
    __syncthreads();
#pragma unroll
    for (int d = 1; d < 256; d <<= 1) {
        int u = (t >= d) ? sh[t - d] : 0;
        __syncthreads();
        sh[t] += u;
        __syncthreads();
    }
    if (t < nb) boff[t] = sh[t] - v;
    if (t == nb - 1) row_start[n] = sh[t];
}

__global__ void k_scan3(const int* __restrict__ cnt, const int* __restrict__ incl,
                        const int* __restrict__ boff, int* __restrict__ row_start,
                        int* __restrict__ cursor, float* __restrict__ dis, int n) {
    int i = blockIdx.x * TPB + threadIdx.x;
    if (i >= n) return;
    int c = cnt[i];
    int ex = boff[i >> 8] + incl[i] - c;
    row_start[i] = ex;
    cursor[i] = ex;
    dis[i] = rsqrtf((float)c + 1.0f);
}

__global__ void k_fill_csr(const int* __restrict__ src, const int* __restrict__ dst,
                           const float* __restrict__ dis, int* __restrict__ cursor,
                           int* __restrict__ csr_src, float* __restrict__ csr_nrm, int E) {
    int e = blockIdx.x * TPB + threadIdx.x;
    if (e >= E) return;
    int s = src[e], d = dst[e];
    int pos = atomicAdd(&cursor[d], 1);
    csr_src[pos] = s;
    csr_nrm[pos] = dis[s] * dis[d];
}

// ---------------- conversions ----------------

__global__ void k_f2bf(const float* __restrict__ in, unsigned short* __restrict__ out, int total8) {
    int i = blockIdx.x * TPB + threadIdx.x;
    if (i >= total8) return;
    float4 f0 = *(const float4*)(in + (size_t)i * 8);
    float4 f1 = *(const float4*)(in + (size_t)i * 8 + 4);
    uint4 o;
    o.x = pack2f(f0.x, f0.y); o.y = pack2f(f0.z, f0.w);
    o.z = pack2f(f1.x, f1.y); o.w = pack2f(f1.z, f1.w);
    *(uint4*)(out + (size_t)i * 8) = o;
}

__global__ void k_cvtT(const float* __restrict__ in, unsigned short* __restrict__ out, int K, int N) {
    int id = blockIdx.x * TPB + threadIdx.x;
    if (id >= K * N) return;
    int k = id / N, nn = id % N;
    out[(size_t)nn * K + k] = (unsigned short)cvt_bf(in[id]);
}

__global__ void k_cvtT_lp(const float* __restrict__ in, unsigned short* __restrict__ out) {
    int id = blockIdx.x * TPB + threadIdx.x;
    if (id >= 1024 * 512) return;
    int j = id >> 9, k = id & 511;
    float v = (j < 512) ? in[(size_t)k * 512 + j] : in[(size_t)(512 + k) * 512 + (j - 512)];
    out[id] = (unsigned short)cvt_bf(v);
}

__global__ __launch_bounds__(256)
void k_bias_lp(const float* __restrict__ lpW1, const float* __restrict__ b2,
               const float* __restrict__ lpb1, float* __restrict__ bias_big) {
    const int j = blockIdx.x * 4 + (threadIdx.x >> 6);
    if (j >= 1024) return;
    const int lane = threadIdx.x & 63;
    const int col = (j < 512) ? j : (j - 512);
    const int ro = (j < 512) ? 0 : 512;
    float s = 0.f;
#pragma unroll
    for (int it = 0; it < 8; ++it) {
        int k = lane + it * 64;
        s = fmaf(b2[k], lpW1[(size_t)(ro + k) * 512 + col], s);
    }
    s += __shfl_xor(s, 1, 64);
    s += __shfl_xor(s, 2, 64);
    s += __shfl_xor(s, 4, 64);
    s += __shfl_xor(s, 8, 64);
    s += __shfl_xor(s, 16, 64);
    s += __shfl_xor(s, 32, 64);
    if (lane == 0) bias_big[j] = s + ((j < 512) ? lpb1[j] : 0.f);
}

// ---------------- CSR gather aggregation (bf16 in, bf16 out) ----------------

__device__ __forceinline__ void fma8(float* acc, uint4 u, float r) {
    acc[0] = fmaf(__uint_as_float(u.x << 16), r, acc[0]);
    acc[1] = fmaf(__uint_as_float(u.x & 0xffff0000u), r, acc[1]);
    acc[2] = fmaf(__uint_as_float(u.y << 16), r, acc[2]);
    acc[3] = fmaf(__uint_as_float(u.y & 0xffff0000u), r, acc[3]);
    acc[4] = fmaf(__uint_as_float(u.z << 16), r, acc[4]);
    acc[5] = fmaf(__uint_as_float(u.z & 0xffff0000u), r, acc[5]);
    acc[6] = fmaf(__uint_as_float(u.w << 16), r, acc[6]);
    acc[7] = fmaf(__uint_as_float(u.w & 0xffff0000u), r, acc[7]);
}

__global__ __launch_bounds__(256)
void k_agg_bf(const unsigned short* __restrict__ xin, const int* __restrict__ row_start,
              const int* __restrict__ csr_src, const float* __restrict__ csr_nrm,
              const float* __restrict__ dis, unsigned short* __restrict__ out, int n) {
    const int v = (blockIdx.x * TPB + threadIdx.x) >> 6;
    if (v >= n) return;
    const int lane = threadIdx.x & 63;
    const uint4* base = (const uint4*)xin;

    float d = dis[v]; float d2 = d * d;
    float acc[8];
    {
        uint4 u = base[(size_t)v * 64 + lane];
        acc[0] = d2 * __uint_as_float(u.x << 16);
        acc[1] = d2 * __uint_as_float(u.x & 0xffff0000u);
        acc[2] = d2 * __uint_as_float(u.y << 16);
        acc[3] = d2 * __uint_as_float(u.y & 0xffff0000u);
        acc[4] = d2 * __uint_as_float(u.z << 16);
        acc[5] = d2 * __uint_as_float(u.z & 0xffff0000u);
        acc[6] = d2 * __uint_as_float(u.w << 16);
        acc[7] = d2 * __uint_as_float(u.w & 0xffff0000u);
    }
    const int beg = row_start[v], end = row_start[v + 1];
    int j = beg;
    for (; j + 1 < end; j += 2) {       // 2 gathers in flight
        int s0 = csr_src[j], s1 = csr_src[j + 1];
        float r0 = csr_nrm[j], r1 = csr_nrm[j + 1];
        uint4 u0 = base[(size_t)s0 * 64 + lane];
        uint4 u1 = base[(size_t)s1 * 64 + lane];
        fma8(acc, u0, r0);
        fma8(acc, u1, r1);
    }
    if (j < end) {
        uint4 u = base[(size_t)csr_src[j] * 64 + lane];
        fma8(acc, u, csr_nrm[j]);
    }
    uint4 o;
    o.x = pack2f(acc[0], acc[1]); o.y = pack2f(acc[2], acc[3]);
    o.z = pack2f(acc[4], acc[5]); o.w = pack2f(acc[6], acc[7]);
    ((uint4*)out)[(size_t)v * 64 + lane] = o;
}

// ---------------- bf16 MFMA GEMM, BK=64, fused bias(+relu), bf16 out ----------------
// C[M,N] = bf16( act( A[M,K] @ Bt[N,K]^T + bias ) )
// 128x128 tile, 4 waves, pre-swizzled global_load_lds staging (two 64B k-halves),
// XCD-swizzled 1-D grid, LDS-staged packed-cvt epilogue.

__global__ __launch_bounds__(256)
void k_gemm_bf(const unsigned short* __restrict__ A, const unsigned short* __restrict__ Bt,
               const float* __restrict__ bias, unsigned short* __restrict__ C,
               int M, int K, int N, int do_relu, int nbx) {
    const int lin = blockIdx.x;
    const int xcd = lin & 7, seq = lin >> 3;
    const int rowt = xcd + 8 * (seq / nbx);
    const int colt = seq % nbx;
    const int m0 = rowt * 128;
    if (m0 >= M + 127) return;
    const int n0 = colt * 128;

    __shared__ __align__(16) char Asl[2 * 128 * 64];   // [kh][row][64B]
    __shared__ __align__(16) char Bsl[2 * 128 * 64];
    const int t = threadIdx.x;
    const int wid = t >> 6, l = t & 63;
    const int wr = (wid >> 1) * 64, wc = (wid & 1) * 64;
    const int lrow = l & 15, g = l >> 4;

    const int srow = (l >> 2);
    const int cb_src = ((l & 3) * 16) ^ ((srow & 3) << 4);
    const int r0 = wid * 32 + srow, r1 = r0 + 16;
    const size_t rowA0 = (size_t)min(m0 + r0, M - 1) * K * 2;
    const size_t rowA1 = (size_t)min(m0 + r1, M - 1) * K * 2;
    const size_t rowB0 = (size_t)(n0 + r0) * K * 2;
    const size_t rowB1 = (size_t)(n0 + r1) * K * 2;
    const char* Ab = (const char*)A;
    const char* Bb = (const char*)Bt;
    char* ldsA0 = Asl + (wid * 32) * 64;
    char* ldsA1 = ldsA0 + 16 * 64;
    char* ldsB0 = Bsl + (wid * 32) * 64;
    char* ldsB1 = ldsB0 + 16 * 64;
    const int rd_off = (g * 16) ^ ((lrow & 3) << 4);

    f32x4 acc[4][4] = {};
    for (int k0 = 0; k0 < K; k0 += 64) {
        const size_t kf0 = (size_t)k0 * 2 + cb_src;
        const size_t kf1 = kf0 + 64;
        gload16(Ab + rowA0 + kf0, ldsA0);
        gload16(Ab + rowA1 + kf0, ldsA1);
        gload16(Ab + rowA0 + kf1, ldsA0 + 8192);
        gload16(Ab + rowA1 + kf1, ldsA1 + 8192);
        gload16(Bb + rowB0 + kf0, ldsB0);
        gload16(Bb + rowB1 + kf0, ldsB1);
        gload16(Bb + rowB0 + kf1, ldsB0 + 8192);
        gload16(Bb + rowB1 + kf1, ldsB1 + 8192);
        __syncthreads();
#pragma unroll
        for (int ks = 0; ks < 2; ++ks) {
            bf16x8 af[4], bfr[4];
#pragma unroll
            for (int i = 0; i < 4; ++i)
                af[i] = *(const bf16x8*)(Asl + ks * 8192 + (wr + i * 16 + lrow) * 64 + rd_off);
#pragma unroll
            for (int j = 0; j < 4; ++j)
                bfr[j] = *(const bf16x8*)(Bsl + ks * 8192 + (wc + j * 16 + lrow) * 64 + rd_off);
#pragma unroll
            for (int i = 0; i < 4; ++i)
#pragma unroll
                for (int j = 0; j < 4; ++j)
                    acc[i][j] = __builtin_amdgcn_mfma_f32_16x16x32_bf16(af[i], bfr[j], acc[i][j], 0, 0, 0);
        }
        __syncthreads();
    }

    // epilogue: bias+relu (f32) -> wave-private LDS [16][64] f32 -> coalesced
    // readback -> packed cvt -> dwordx4 stores. No cross-wave barriers needed.
    float bv[4];
#pragma unroll
    for (int j = 0; j < 4; ++j) bv[j] = bias[n0 + wc + j * 16 + lrow];
    float* lws = (float*)Asl + wid * 1024;          // 4KB per wave
    const int rrow = l >> 2, rcol = (l & 3) * 16;   // readback mapping
#pragma unroll
    for (int i = 0; i < 4; ++i) {
#pragma unroll
        for (int e = 0; e < 4; ++e)
#pragma unroll
            for (int j = 0; j < 4; ++j) {
                float vv = acc[i][j][e] + bv[j];
                if (do_relu) vv = fmaxf(vv, 0.f);
                lws[(g * 4 + e) * 64 + j * 16 + lrow] = vv;
            }
        asm volatile("s_waitcnt lgkmcnt(0)" ::: "memory");
        __builtin_amdgcn_sched_barrier(0);
        const int grow = m0 + wr + i * 16 + rrow;
        float4 f0 = *(const float4*)&lws[rrow * 64 + rcol];
        float4 f1 = *(const float4*)&lws[rrow * 64 + rcol + 4];
        float4 f2 = *(const float4*)&lws[rrow * 64 + rcol + 8];
        float4 f3 = *(const float4*)&lws[rrow * 64 + rcol + 12];
        if (grow < M) {
            uint4 o0, o1;
            o0.x = pack2f(f0.x, f0.y); o0.y = pack2f(f0.z, f0.w);
            o0.z = pack2f(f1.x, f1.y); o0.w = pack2f(f1.z, f1.w);
            o1.x = pack2f(f2.x, f2.y); o1.y = pack2f(f2.z, f2.w);
            o1.z = pack2f(f3.x, f3.y); o1.w = pack2f(f3.z, f3.w);
            *(uint4*)(C + (size_t)grow * N + n0 + wc + rcol)     = o0;
            *(uint4*)(C + (size_t)grow * N + n0 + wc + rcol + 8) = o1;
        }
        asm volatile("s_waitcnt lgkmcnt(0)" ::: "memory");  // reads done before next overwrite
        __builtin_amdgcn_sched_barrier(0);
    }
}

// ---------------- pair pass: out = sigmoid( relu(u'[p0]+v[p1]) . w2 + lpb2 ) ----------------

__global__ __launch_bounds__(256)
void k_pair(const unsigned short* __restrict__ uv, const int* __restrict__ pair, int P,
            const float* __restrict__ w2, const float* __restrict__ lpb2,
            float* __restrict__ out) {
    const int idx = (blockIdx.x * TPB + threadIdx.x) >> 6;
    if (idx >= P) return;
    const int lane = threadIdx.x & 63;
    const int p0n = pair[idx], p1n = pair[P + idx];
    const uint4 a = *(const uint4*)(uv + (size_t)p0n * 1024 + lane * 8);
    const uint4 b = *(const uint4*)(uv + (size_t)p1n * 1024 + 512 + lane * 8);
    const float4 w0 = *(const float4*)(w2 + lane * 8);
    const float4 w1 = *(const float4*)(w2 + lane * 8 + 4);
    const unsigned ua[4] = {a.x, a.y, a.z, a.w};
    const unsigned ub[4] = {b.x, b.y, b.z, b.w};
    const float wv[8] = {w0.x, w0.y, w0.z, w0.w, w1.x, w1.y, w1.z, w1.w};
    float s = 0.f;
#pragma unroll
    for (int q = 0; q < 4; ++q) {
        float h0 = __uint_as_float(ua[q] << 16) + __uint_as_float(ub[q] << 16);
        float h1 = __uint_as_float(ua[q] & 0xffff0000u) + __uint_as_float(ub[q] & 0xffff0000u);
        s = fmaf(fmaxf(h0, 0.f), wv[2 * q], s);
        s = fmaf(fmaxf(h1, 0.f), wv[2 * q + 1], s);
    }
    s += __shfl_xor(s, 1, 64);
    s += __shfl_xor(s, 2, 64);
    s += __shfl_xor(s, 4, 64);
    s += __shfl_xor(s, 8, 64);
    s += __shfl_xor(s, 16, 64);
    s += __shfl_xor(s, 32, 64);
    if (lane == 0) out[idx] = 1.0f / (1.0f + expf(-(s + lpb2[0])));
}

// ---------------- launcher ----------------

extern "C" void kernel_launch(void* const* d_in, const int* in_sizes, int n_in,
                              void* d_out, int out_size, void* d_ws, size_t ws_size,
                              hipStream_t stream) {
    const float* x    = (const float*)d_in[0];
    const int*   ei   = (const int*)d_in[1];
    const int*   ep   = (const int*)d_in[2];
    const float* W1   = (const float*)d_in[3];
    const float* b1   = (const float*)d_in[4];
    const float* W2   = (const float*)d_in[5];
    const float* b2   = (const float*)d_in[6];
    const float* lpW1 = (const float*)d_in[7];
    const float* lpb1 = (const float*)d_in[8];
    const float* lpW2 = (const float*)d_in[9];
    const float* lpb2 = (const float*)d_in[10];

    const int n = in_sizes[0] / 512;
    const int E = in_sizes[1] / 2;
    const int P = in_sizes[2] / 2;
    const int* src = ei;
    const int* dst = ei + E;

    char* w = (char*)d_ws;
    size_t off = 0;
    auto alloc = [&](size_t bytes) {
        void* p = w + off;
        off = (off + bytes + 255) & ~(size_t)255;
        return p;
    };
    int*   cnt       = (int*)alloc((size_t)n * 4);
    int*   incl      = (int*)alloc((size_t)n * 4);
    int*   bsum      = (int*)alloc((size_t)256 * 4);
    int*   boff      = (int*)alloc((size_t)256 * 4);
    int*   row_start = (int*)alloc((size_t)(n + 1) * 4);
    int*   cursor    = (int*)alloc((size_t)n * 4);
    int*   csr_src   = (int*)alloc((size_t)E * 4);
    float* csr_nrm   = (float*)alloc((size_t)E * 4);
    float* dis       = (float*)alloc((size_t)n * 4);
    unsigned short* w1t    = (unsigned short*)alloc((size_t)512 * 512 * 2);
    unsigned short* w2bf   = (unsigned short*)alloc((size_t)512 * 512 * 2);
    unsigned short* lpw1t  = (unsigned short*)alloc((size_t)1024 * 512 * 2);
    unsigned short* wfT    = (unsigned short*)alloc((size_t)1024 * 512 * 2);
    float* bias_big  = (float*)alloc((size_t)1024 * 4);
    float* zerob     = (float*)alloc((size_t)1024 * 4);
    unsigned short* bufA = (unsigned short*)alloc((size_t)n * 512 * 2);
    unsigned short* bufB = (unsigned short*)alloc((size_t)n * 512 * 2);
    unsigned short* uv   = (unsigned short*)alloc((size_t)n * 1024 * 2);

    dim3 blk(TPB);
    const int nb_n = (n + TPB - 1) / TPB;
    const int nb_E = (E + TPB - 1) / TPB;
    const int nb_scan = (n + 255) / 256;

    // CSR build + norms
    (void)hipMemsetAsync(cnt, 0, (size_t)n * 4, stream);
    (void)hipMemsetAsync(zerob, 0, (size_t)1024 * 4, stream);
    k_hist<<<nb_E, blk, 0, stream>>>(dst, cnt, E);
    k_scan1<<<nb_scan, 256, 0, stream>>>(cnt, incl, bsum, n);
    k_scan2<<<1, 256, 0, stream>>>(bsum, boff, row_start, n, nb_scan);
    k_scan3<<<nb_n, blk, 0, stream>>>(cnt, incl, boff, row_start, cursor, dis, n);
    k_fill_csr<<<nb_E, blk, 0, stream>>>(src, dst, dis, cursor, csr_src, csr_nrm, E);

    // conversions + weight fusion prep
    k_f2bf<<<(n * 64 + TPB - 1) / TPB, blk, 0, stream>>>(x, bufA, n * 64);
    k_cvtT<<<(512 * 512 + TPB - 1) / TPB, blk, 0, stream>>>(W1, w1t, 512, 512);
    k_f2bf<<<(512 * 64 + TPB - 1) / TPB, blk, 0, stream>>>(W2, w2bf, 512 * 64);
    k_cvtT_lp<<<(1024 * 512 + TPB - 1) / TPB, blk, 0, stream>>>(lpW1, lpw1t);
    k_bias_lp<<<256, blk, 0, stream>>>(lpW1, b2, lpb1, bias_big);

    const int gy  = (n + 127) / 128;
    const int gy8 = ((gy + 7) / 8) * 8;
    const int agg_blocks = (n * 64 + TPB - 1) / TPB;

    // WfusedT[j][i] = sum_k lpW1ext[k][j] * W2[i][k]  -> [1024,512] bf16 Bt layout
    k_gemm_bf<<<4 * 8, blk, 0, stream>>>(lpw1t, w2bf, zerob, wfT, 1024, 512, 512, 0, 4);

    // layer 1: y1 = A_hat x ; z1 = relu(y1 @ W1 + b1)
    k_agg_bf<<<agg_blocks, blk, 0, stream>>>(bufA, row_start, csr_src, csr_nrm, dis, bufB, n);
    k_gemm_bf<<<4 * gy8, blk, 0, stream>>>(bufB, w1t, b1, bufA, n, 512, 512, 1, 4);
    // layer 2 folded into LP node-GEMM: y2 = A_hat z1 ; uv = y2 @ Wfused + bias_big
    k_agg_bf<<<agg_blocks, blk, 0, stream>>>(bufA, row_start, csr_src, csr_nrm, dis, bufB, n);
    k_gemm_bf<<<8 * gy8, blk, 0, stream>>>(bufB, wfT, bias_big, uv, n, 512, 1024, 0, 8);

    // pair pass (fused relu + dot + sigmoid)
    k_pair<<<(P * 64 + TPB - 1) / TPB, blk, 0, stream>>>(uv, ep, P, lpW2, lpb2, (float*)d_out);
}